// Round 1
// baseline (991.840 us; speedup 1.0000x reference)
//
#include <hip/hip_runtime.h>
#include <hip/hip_bf16.h>

#define DIN 768
#define DH  256

__device__ inline float wave_sum(float v) {
#pragma unroll
  for (int o = 32; o; o >>= 1) v += __shfl_xor(v, o);
  return v;
}
__device__ inline float wave_max(float v) {
#pragma unroll
  for (int o = 32; o; o >>= 1) v = fmaxf(v, __shfl_xor(v, o));
  return v;
}
__device__ inline float leaky(float v) { return v > 0.f ? v : 0.2f * v; }

// ---------------- K1: cosine relevance gating ----------------
__global__ __launch_bounds__(256) void rel_kernel(
    const float* __restrict__ ce, const float* __restrict__ x,
    const int* __restrict__ batch, float* __restrict__ rel, int n) {
  int node = blockIdx.x * 4 + (threadIdx.x >> 6);
  int lane = threadIdx.x & 63;
  if (node >= n) return;
  int g = batch[node];
  const float4* xr = (const float4*)(x + (size_t)node * DIN);
  const float4* cr = (const float4*)(ce + (size_t)g * DIN);
  float dxy = 0.f, dxx = 0.f, dcc = 0.f;
#pragma unroll
  for (int i = 0; i < 3; i++) {
    float4 a = xr[lane + 64 * i];
    float4 b = cr[lane + 64 * i];
    dxy += a.x*b.x + a.y*b.y + a.z*b.z + a.w*b.w;
    dxx += a.x*a.x + a.y*a.y + a.z*a.z + a.w*a.w;
    dcc += b.x*b.x + b.y*b.y + b.z*b.z + b.w*b.w;
  }
  dxy = wave_sum(dxy);
  dxx = wave_sum(dxx);
  dcc = wave_sum(dcc);
  if (lane == 0) {
    float denom = fmaxf(sqrtf(dxx) * sqrtf(dcc), 1e-8f);
    rel[node] = dxy / denom;
  }
}

// ---------------- CSR build: histogram, scan, fill ----------------
__global__ void hist_kernel(const int* __restrict__ dst, int E, int* __restrict__ cnt) {
  for (int e = blockIdx.x * blockDim.x + threadIdx.x; e < E; e += gridDim.x * blockDim.x)
    atomicAdd(&cnt[dst[e]], 1);
}

__global__ __launch_bounds__(1024) void scan_kernel(const int* __restrict__ cnt,
                                                    int* __restrict__ row_off, int n) {
  __shared__ int s[1024];
  int t = threadIdx.x;
  int chunk = (n + 1023) / 1024;
  int lo = t * chunk, hi = min(lo + chunk, n);
  int sum = 0;
  for (int i = lo; i < hi; i++) sum += cnt[i];
  int mysum = sum;
  s[t] = sum;
  __syncthreads();
  for (int off = 1; off < 1024; off <<= 1) {
    int v = (t >= off) ? s[t - off] : 0;
    __syncthreads();
    s[t] += v;
    __syncthreads();
  }
  int run = s[t] - mysum;  // exclusive prefix of my chunk
  for (int i = lo; i < hi; i++) { row_off[i] = run; run += cnt[i]; }
  if (t == 1023) row_off[n] = s[1023];
}

__global__ void fill_kernel(const int* __restrict__ src, const int* __restrict__ dst, int E,
                            const int* __restrict__ row_off, int* __restrict__ fill,
                            int* __restrict__ col_src) {
  for (int e = blockIdx.x * blockDim.x + threadIdx.x; e < E; e += gridDim.x * blockDim.x) {
    int d = dst[e];
    int slot = row_off[d] + atomicAdd(&fill[d], 1);
    col_src[slot] = src[e];
  }
}

// ---------------- GEMM: out[n,256] = rowscale * (A[n,K] @ W[K,256]) ----------------
template <int KDIM>
__global__ __launch_bounds__(256) void gemm_rowscale(
    const float* __restrict__ A, const float* __restrict__ W,
    const float* __restrict__ scale, float* __restrict__ out, int n) {
  constexpr int BK = 16;
  __shared__ float As[BK][68];   // transposed A tile (padded: 2-way banks max)
  __shared__ float Ws[BK][256];
  int tid = threadIdx.x;
  int tx = tid & 31;   // col group: cols tx*4..+3 and 128+tx*4..+3
  int ty = tid >> 5;   // row group: rows ty*8..+7
  int row0 = blockIdx.x * 64;

  float acc[8][8];
#pragma unroll
  for (int r = 0; r < 8; r++)
#pragma unroll
    for (int c = 0; c < 8; c++) acc[r][c] = 0.f;

  for (int k0 = 0; k0 < KDIM; k0 += BK) {
    // A tile: 64 rows x 16 k, transposed into As[k][r]
    {
      int r = tid >> 2;
      int kq = tid & 3;
      int row = row0 + r;
      float4 a4 = make_float4(0.f, 0.f, 0.f, 0.f);
      if (row < n) a4 = *(const float4*)&A[(size_t)row * KDIM + k0 + kq * 4];
      As[kq * 4 + 0][r] = a4.x;
      As[kq * 4 + 1][r] = a4.y;
      As[kq * 4 + 2][r] = a4.z;
      As[kq * 4 + 3][r] = a4.w;
    }
    // W tile: 16 x 256
#pragma unroll
    for (int i = 0; i < 4; i++) {
      int idx = tid + i * 256;   // float4 index 0..1023
      int kk = idx >> 6;
      int c4 = idx & 63;
      *(float4*)&Ws[kk][c4 * 4] = *(const float4*)&W[(size_t)(k0 + kk) * 256 + c4 * 4];
    }
    __syncthreads();
#pragma unroll
    for (int k = 0; k < BK; k++) {
      float4 a0 = *(const float4*)&As[k][ty * 8];
      float4 a1 = *(const float4*)&As[k][ty * 8 + 4];
      float4 w0 = *(const float4*)&Ws[k][tx * 4];
      float4 w1 = *(const float4*)&Ws[k][128 + tx * 4];
      float a[8] = {a0.x, a0.y, a0.z, a0.w, a1.x, a1.y, a1.z, a1.w};
      float wv[8] = {w0.x, w0.y, w0.z, w0.w, w1.x, w1.y, w1.z, w1.w};
#pragma unroll
      for (int r = 0; r < 8; r++)
#pragma unroll
        for (int c = 0; c < 8; c++) acc[r][c] = fmaf(a[r], wv[c], acc[r][c]);
    }
    __syncthreads();
  }
  // epilogue
#pragma unroll
  for (int r = 0; r < 8; r++) {
    int row = row0 + ty * 8 + r;
    if (row >= n) break;
    float s = scale ? scale[row] : 1.0f;
    float4 o0 = make_float4(acc[r][0] * s, acc[r][1] * s, acc[r][2] * s, acc[r][3] * s);
    float4 o1 = make_float4(acc[r][4] * s, acc[r][5] * s, acc[r][6] * s, acc[r][7] * s);
    *(float4*)&out[(size_t)row * 256 + tx * 4] = o0;
    *(float4*)&out[(size_t)row * 256 + 128 + tx * 4] = o1;
  }
}

// ---------------- alpha: per-row dots with a_src / a_dst ----------------
__global__ __launch_bounds__(256) void alpha_kernel(
    const float* __restrict__ h, const float* __restrict__ a_s,
    const float* __restrict__ a_d, float* __restrict__ alpha_s,
    float* __restrict__ alpha_d, int n) {
  int node = blockIdx.x * 4 + (threadIdx.x >> 6);
  int lane = threadIdx.x & 63;
  if (node >= n) return;
  float4 hv = ((const float4*)h)[(size_t)node * 64 + lane];
  float4 sv = ((const float4*)a_s)[lane];
  float4 dv = ((const float4*)a_d)[lane];
  float ps = hv.x * sv.x + hv.y * sv.y + hv.z * sv.z + hv.w * sv.w;
  float pd = hv.x * dv.x + hv.y * dv.y + hv.z * dv.z + hv.w * dv.w;
  ps = wave_sum(ps);
  pd = wave_sum(pd);
  if (lane == 0) {
    alpha_s[node] = ps;
    alpha_d[node] = pd;
  }
}

// ---------------- GAT attention + aggregation (wave per node) ----------------
__global__ __launch_bounds__(256) void gat_agg(
    const float* __restrict__ hw, const float* __restrict__ as_,
    const float* __restrict__ ad_, const int* __restrict__ row_off,
    const int* __restrict__ col_src, const float* __restrict__ bias,
    float* __restrict__ out, int n, int relu_out) {
  int node = blockIdx.x * 4 + (threadIdx.x >> 6);
  int lane = threadIdx.x & 63;
  if (node >= n) return;
  int lo = row_off[node], hi = row_off[node + 1];
  int deg = hi - lo;
  float adn = ad_[node];
  float self_e = leaky(as_[node] + adn);

  // phase A: running max (self included via init)
  float m = self_e;
  for (int e = lane; e < deg; e += 64) {
    int s = col_src[lo + e];
    m = fmaxf(m, leaky(as_[s] + adn));
  }
  m = wave_max(m);

  // phase B: sum of exp
  float z = 0.f;
  for (int e = lane; e < deg; e += 64) {
    int s = col_src[lo + e];
    z += __expf(leaky(as_[s] + adn) - m);
  }
  z = wave_sum(z);
  float ez_self = __expf(self_e - m);
  z += ez_self;
  float inv_z = 1.0f / z;

  // phase C: weighted row accumulation (float4 per lane = 256 cols)
  const float4* h4 = (const float4*)hw;
  float4 hv = h4[(size_t)node * 64 + lane];
  float ws = ez_self * inv_z;
  float4 acc = make_float4(hv.x * ws, hv.y * ws, hv.z * ws, hv.w * ws);
  for (int e = 0; e < deg; e++) {
    int s = col_src[lo + e];
    float wgt = __expf(leaky(as_[s] + adn) - m) * inv_z;
    float4 v = h4[(size_t)s * 64 + lane];
    acc.x = fmaf(wgt, v.x, acc.x);
    acc.y = fmaf(wgt, v.y, acc.y);
    acc.z = fmaf(wgt, v.z, acc.z);
    acc.w = fmaf(wgt, v.w, acc.w);
  }
  float4 bb = ((const float4*)bias)[lane];
  acc.x += bb.x; acc.y += bb.y; acc.z += bb.z; acc.w += bb.w;
  if (relu_out) {
    acc.x = fmaxf(acc.x, 0.f); acc.y = fmaxf(acc.y, 0.f);
    acc.z = fmaxf(acc.z, 0.f); acc.w = fmaxf(acc.w, 0.f);
  }
  ((float4*)out)[(size_t)node * 64 + lane] = acc;
}

// ---------------- BN stats: per-column sum / sumsq ----------------
__global__ __launch_bounds__(256) void bn_stats(const float* __restrict__ h, int n,
                                                float* __restrict__ bsum,
                                                float* __restrict__ bsq) {
  int c = threadIdx.x;
  int rows_per_block = (n + gridDim.x - 1) / gridDim.x;
  int r0 = blockIdx.x * rows_per_block;
  int r1 = min(r0 + rows_per_block, n);
  float sum = 0.f, sq = 0.f;
  for (int r = r0; r < r1; r++) {
    float v = h[(size_t)r * 256 + c];
    sum += v;
    sq = fmaf(v, v, sq);
  }
  atomicAdd(&bsum[c], sum);
  atomicAdd(&bsq[c], sq);
}

// ---------------- BN apply + ReLU (in place) ----------------
__global__ __launch_bounds__(256) void bn_apply(float* __restrict__ h,
                                                const float* __restrict__ bsum,
                                                const float* __restrict__ bsq,
                                                const float* __restrict__ gamma,
                                                const float* __restrict__ beta, int n) {
  int total4 = n * 64;
  float inv_n = 1.0f / (float)n;
  for (int f = blockIdx.x * blockDim.x + threadIdx.x; f < total4;
       f += gridDim.x * blockDim.x) {
    int c4 = f & 63;
    float4 v = ((float4*)h)[f];
    float4 sm = ((const float4*)bsum)[c4];
    float4 sl = ((const float4*)bsq)[c4];
    float4 g = ((const float4*)gamma)[c4];
    float4 bb = ((const float4*)beta)[c4];
    float m, var;
    m = sm.x * inv_n; var = sl.x * inv_n - m * m;
    v.x = fmaxf(g.x * (v.x - m) * rsqrtf(var + 1e-5f) + bb.x, 0.f);
    m = sm.y * inv_n; var = sl.y * inv_n - m * m;
    v.y = fmaxf(g.y * (v.y - m) * rsqrtf(var + 1e-5f) + bb.y, 0.f);
    m = sm.z * inv_n; var = sl.z * inv_n - m * m;
    v.z = fmaxf(g.z * (v.z - m) * rsqrtf(var + 1e-5f) + bb.z, 0.f);
    m = sm.w * inv_n; var = sl.w * inv_n - m * m;
    v.w = fmaxf(g.w * (v.w - m) * rsqrtf(var + 1e-5f) + bb.w, 0.f);
    ((float4*)h)[f] = v;
  }
}

// ---------------- mean pool per graph (batch is sorted) ----------------
__device__ inline int lower_bound_dev(const int* a, int n, int v) {
  int lo = 0, hi = n;
  while (lo < hi) {
    int mid = (lo + hi) >> 1;
    if (a[mid] < v) lo = mid + 1; else hi = mid;
  }
  return lo;
}

__global__ __launch_bounds__(256) void pool_kernel(const float* __restrict__ h,
                                                   const int* __restrict__ batch, int n,
                                                   float* __restrict__ pooled) {
  int g = blockIdx.x;
  int lo = lower_bound_dev(batch, n, g);
  int hi = lower_bound_dev(batch, n, g + 1);
  float sum = 0.f;
  for (int r = lo; r < hi; r++) sum += h[(size_t)r * 256 + threadIdx.x];
  pooled[(size_t)g * 256 + threadIdx.x] = sum / fmaxf((float)(hi - lo), 1.0f);
}

// ---------------- final head: concat(pooled, ce) @ Wc + bc ----------------
__global__ __launch_bounds__(256) void final_kernel(const float* __restrict__ pooled,
                                                    const float* __restrict__ ce,
                                                    const float* __restrict__ Wc,
                                                    const float* __restrict__ bc,
                                                    float* __restrict__ out, int B) {
  int g = blockIdx.x;
  int t = threadIdx.x;
  float p = 0.f;
  p = fmaf(pooled[(size_t)g * 256 + t], Wc[t], p);
  p = fmaf(ce[(size_t)g * 768 + t],        Wc[256 + t], p);
  p = fmaf(ce[(size_t)g * 768 + 256 + t],  Wc[512 + t], p);
  p = fmaf(ce[(size_t)g * 768 + 512 + t],  Wc[768 + t], p);
  __shared__ float red[256];
  red[t] = p;
  __syncthreads();
  for (int s = 128; s; s >>= 1) {
    if (t < s) red[t] += red[t + s];
    __syncthreads();
  }
  if (t == 0) out[g] = red[0] + bc[0];
}

// ---------------- launch ----------------
extern "C" void kernel_launch(void* const* d_in, const int* in_sizes, int n_in,
                              void* d_out, int out_size, void* d_ws, size_t ws_size,
                              hipStream_t stream) {
  const float* ce    = (const float*)d_in[0];
  const float* x     = (const float*)d_in[1];
  const int*   edge  = (const int*)d_in[2];
  const int*   batch = (const int*)d_in[3];
  const float* W1    = (const float*)d_in[4];
  const float* a_s1  = (const float*)d_in[5];
  const float* a_d1  = (const float*)d_in[6];
  const float* b1    = (const float*)d_in[7];
  const float* W2    = (const float*)d_in[8];
  const float* a_s2  = (const float*)d_in[9];
  const float* a_d2  = (const float*)d_in[10];
  const float* b2    = (const float*)d_in[11];
  const float* gamma = (const float*)d_in[12];
  const float* beta  = (const float*)d_in[13];
  const float* Wc    = (const float*)d_in[14];
  const float* bc    = (const float*)d_in[15];

  const int B = in_sizes[0] / DIN;
  const int n = in_sizes[1] / DIN;
  const int E = in_sizes[2] / 2;
  const int* esrc = edge;
  const int* edst = edge + E;

  char* w = (char*)d_ws;
  size_t off = 0;
  auto carve = [&](size_t bytes) -> void* {
    void* p = w + off;
    off = (off + bytes + 255) & ~(size_t)255;
    return p;
  };
  float* rel     = (float*)carve((size_t)n * 4);
  float* alpha_s = (float*)carve((size_t)n * 4);
  float* alpha_d = (float*)carve((size_t)n * 4);
  int*   cnt     = (int*)carve((size_t)n * 4);
  int*   row_off = (int*)carve((size_t)(n + 1) * 4);
  int*   fill    = (int*)carve((size_t)n * 4);
  int*   col_src = (int*)carve((size_t)E * 4);
  float* bn_sum  = (float*)carve(DH * 4);
  float* bn_sq   = (float*)carve(DH * 4);
  float* pooled  = (float*)carve((size_t)B * DH * 4);
  float* buf_h   = (float*)carve((size_t)n * DH * 4);
  float* buf_o   = (float*)carve((size_t)n * DH * 4);

  // per-call zero init (ws is NOT re-poisoned between replays)
  hipMemsetAsync(cnt, 0, (size_t)n * 4, stream);
  hipMemsetAsync(fill, 0, (size_t)n * 4, stream);
  hipMemsetAsync(bn_sum, 0, DH * 4, stream);
  hipMemsetAsync(bn_sq, 0, DH * 4, stream);

  const int gN4 = (n + 3) / 4;

  // cosine gate
  rel_kernel<<<gN4, 256, 0, stream>>>(ce, x, batch, rel, n);

  // CSR build (real edges only; self-loops handled inline in gat_agg)
  hist_kernel<<<1024, 256, 0, stream>>>(edst, E, cnt);
  scan_kernel<<<1, 1024, 0, stream>>>(cnt, row_off, n);
  fill_kernel<<<1024, 256, 0, stream>>>(esrc, edst, E, row_off, fill, col_src);

  // ---- layer 1 ----
  gemm_rowscale<DIN><<<(n + 63) / 64, 256, 0, stream>>>(x, W1, rel, buf_h, n);
  alpha_kernel<<<gN4, 256, 0, stream>>>(buf_h, a_s1, a_d1, alpha_s, alpha_d, n);
  gat_agg<<<gN4, 256, 0, stream>>>(buf_h, alpha_s, alpha_d, row_off, col_src, b1,
                                   buf_o, n, 0);
  bn_stats<<<512, 256, 0, stream>>>(buf_o, n, bn_sum, bn_sq);
  bn_apply<<<2048, 256, 0, stream>>>(buf_o, bn_sum, bn_sq, gamma, beta, n);

  // ---- layer 2 ----
  gemm_rowscale<DH><<<(n + 63) / 64, 256, 0, stream>>>(buf_o, W2, nullptr, buf_h, n);
  alpha_kernel<<<gN4, 256, 0, stream>>>(buf_h, a_s2, a_d2, alpha_s, alpha_d, n);
  gat_agg<<<gN4, 256, 0, stream>>>(buf_h, alpha_s, alpha_d, row_off, col_src, b2,
                                   buf_o, n, 1);

  // ---- head ----
  pool_kernel<<<B, 256, 0, stream>>>(buf_o, batch, n, pooled);
  final_kernel<<<B, 256, 0, stream>>>(pooled, ce, Wc, bc, (float*)d_out, B);
}

// Round 2
// 778.260 us; speedup vs baseline: 1.2744x; 1.2744x over previous
//
#include <hip/hip_runtime.h>
#include <hip/hip_bf16.h>

#define DIN 768
#define DH  256

typedef unsigned short ushort_t;
typedef __attribute__((ext_vector_type(8))) short short8v;   // 8 bf16 (4 VGPRs)
typedef __attribute__((ext_vector_type(4))) float f32x4;

__device__ inline float wave_sum(float v) {
#pragma unroll
  for (int o = 32; o; o >>= 1) v += __shfl_xor(v, o);
  return v;
}
__device__ inline float wave_max(float v) {
#pragma unroll
  for (int o = 32; o; o >>= 1) v = fmaxf(v, __shfl_xor(v, o));
  return v;
}
__device__ inline float leaky(float v) { return v > 0.f ? v : 0.2f * v; }

__device__ inline ushort_t f2bf(float f) {
  union { float f; unsigned u; } v; v.f = f;
  unsigned r = v.u + 0x7FFFu + ((v.u >> 16) & 1u);  // RNE
  return (ushort_t)(r >> 16);
}

// ---------------- K1: cosine relevance gating + bf16(x*rel) ----------------
__global__ __launch_bounds__(256) void relxb_kernel(
    const float* __restrict__ ce, const float* __restrict__ x,
    const int* __restrict__ batch, ushort_t* __restrict__ xb, int n) {
  int node = blockIdx.x * 4 + (threadIdx.x >> 6);
  int lane = threadIdx.x & 63;
  if (node >= n) return;
  int g = batch[node];
  const float4* xr = (const float4*)(x + (size_t)node * DIN);
  const float4* cr = (const float4*)(ce + (size_t)g * DIN);
  float4 av[3];
  float dxy = 0.f, dxx = 0.f, dcc = 0.f;
#pragma unroll
  for (int i = 0; i < 3; i++) {
    float4 a = xr[lane + 64 * i];
    float4 b = cr[lane + 64 * i];
    av[i] = a;
    dxy += a.x*b.x + a.y*b.y + a.z*b.z + a.w*b.w;
    dxx += a.x*a.x + a.y*a.y + a.z*a.z + a.w*a.w;
    dcc += b.x*b.x + b.y*b.y + b.z*b.z + b.w*b.w;
  }
  dxy = wave_sum(dxy);
  dxx = wave_sum(dxx);
  dcc = wave_sum(dcc);
  float denom = fmaxf(sqrtf(dxx) * sqrtf(dcc), 1e-8f);
  float rel = dxy / denom;
#pragma unroll
  for (int i = 0; i < 3; i++) {
    float4 a = av[i];
    ushort4 o = make_ushort4(f2bf(a.x * rel), f2bf(a.y * rel),
                             f2bf(a.z * rel), f2bf(a.w * rel));
    *(ushort4*)&xb[(size_t)node * DIN + (lane + 64 * i) * 4] = o;
  }
}

// ---------------- W transpose + bf16 cast: W[K][256] -> Wt[256][K] ----------------
__global__ void wt_kernel(const float* __restrict__ W, ushort_t* __restrict__ Wt, int K) {
  int k = blockIdx.x * 256 + threadIdx.x;
  if (k >= K) return;
  for (int c = 0; c < 256; c++)
    Wt[(size_t)c * K + k] = f2bf(W[(size_t)k * 256 + c]);
}

// ---------------- CSR build: histogram, scan, fill ----------------
__global__ void hist_kernel(const int* __restrict__ dst, int E, int* __restrict__ cnt) {
  for (int e = blockIdx.x * blockDim.x + threadIdx.x; e < E; e += gridDim.x * blockDim.x)
    atomicAdd(&cnt[dst[e]], 1);
}

__global__ __launch_bounds__(1024) void scan_kernel(const int* __restrict__ cnt,
                                                    int* __restrict__ row_off, int n) {
  __shared__ int s[1024];
  int t = threadIdx.x;
  int chunk = (n + 1023) / 1024;
  int lo = t * chunk, hi = min(lo + chunk, n);
  int sum = 0;
  for (int i = lo; i < hi; i++) sum += cnt[i];
  int mysum = sum;
  s[t] = sum;
  __syncthreads();
  for (int off = 1; off < 1024; off <<= 1) {
    int v = (t >= off) ? s[t - off] : 0;
    __syncthreads();
    s[t] += v;
    __syncthreads();
  }
  int run = s[t] - mysum;
  for (int i = lo; i < hi; i++) { row_off[i] = run; run += cnt[i]; }
  if (t == 1023) row_off[n] = s[1023];
}

__global__ void fill_kernel(const int* __restrict__ src, const int* __restrict__ dst, int E,
                            const int* __restrict__ row_off, int* __restrict__ fill,
                            int* __restrict__ col_src) {
  for (int e = blockIdx.x * blockDim.x + threadIdx.x; e < E; e += gridDim.x * blockDim.x) {
    int d = dst[e];
    int slot = row_off[d] + atomicAdd(&fill[d], 1);
    col_src[slot] = src[e];
  }
}

// ---------------- bf16 MFMA GEMM: C[M,256] = A[M,K] @ Bt[256,K]^T ----------------
// A row-major bf16, Bt = W^T row-major bf16 ([col][k]).
// 128x128 tile, BK=64, 4 waves (2x2), each wave 64x64 via 4x4 frags of 16x16x32.
// LDS layout per operand: [kb=0..7][row=0..127][kk=0..7] bf16 -> contiguous
// 16B per (row,kb), so global_load_lds lane*16B mapping and ds_read_b128 both
// hit the contiguous conflict-free pattern.
template <int K>
__global__ __launch_bounds__(256) void gemm_mfma(
    const ushort_t* __restrict__ A, const ushort_t* __restrict__ Bt,
    float* __restrict__ C, int Mreal) {
  __shared__ ushort_t lds[16384];  // A: [0,8192) shorts, B: [8192,16384)
  const int tid = threadIdx.x;
  const int lane = tid & 63;
  const int wave = tid >> 6;
  const int row0 = blockIdx.x * 128;
  const int col0 = blockIdx.y * 128;
  const int wr = wave >> 1, wc = wave & 1;

  f32x4 acc[4][4];
#pragma unroll
  for (int m = 0; m < 4; m++)
#pragma unroll
    for (int nn = 0; nn < 4; nn++)
#pragma unroll
      for (int j = 0; j < 4; j++) acc[m][nn][j] = 0.f;

  for (int k0 = 0; k0 < K; k0 += 64) {
    // stage 32 KB: 32 chunks of 1 KB (64 lanes x 16B); 8 chunks per wave
#pragma unroll
    for (int c = 0; c < 8; c++) {
      int chunk = wave * 8 + c;
      int isB = chunk >> 4;
      int i = chunk & 15;
      int kb = i >> 1, half = i & 1;
      int ldsbase = isB * 8192 + kb * 1024 + half * 512;  // in shorts
      const ushort_t* gsrc;
      int grow = half * 64 + lane;
      if (isB == 0) {
        int r = row0 + grow;
        r = r < Mreal ? r : Mreal - 1;  // clamp tail rows (stores are guarded)
        gsrc = A + (size_t)r * K + k0 + kb * 8;
      } else {
        gsrc = Bt + (size_t)(col0 + grow) * K + k0 + kb * 8;
      }
      __builtin_amdgcn_global_load_lds(
          (const __attribute__((address_space(1))) void*)gsrc,
          (__attribute__((address_space(3))) void*)&lds[ldsbase], 16, 0, 0);
    }
    __syncthreads();  // drains vmcnt before barrier (compiler-inserted)
#pragma unroll
    for (int ks = 0; ks < 2; ks++) {
      short8v a[4], b[4];
#pragma unroll
      for (int m = 0; m < 4; m++) {
        int idx = (ks * 4 + (lane >> 4)) * 1024 + (wr * 64 + m * 16 + (lane & 15)) * 8;
        a[m] = *(const short8v*)&lds[idx];
      }
#pragma unroll
      for (int nn = 0; nn < 4; nn++) {
        int idx = 8192 + (ks * 4 + (lane >> 4)) * 1024 +
                  (wc * 64 + nn * 16 + (lane & 15)) * 8;
        b[nn] = *(const short8v*)&lds[idx];
      }
#pragma unroll
      for (int m = 0; m < 4; m++)
#pragma unroll
        for (int nn = 0; nn < 4; nn++)
          acc[m][nn] = __builtin_amdgcn_mfma_f32_16x16x32_bf16(a[m], b[nn],
                                                               acc[m][nn], 0, 0, 0);
    }
    __syncthreads();
  }
  // epilogue: C/D layout col=lane&15, row=(lane>>4)*4+j  [m89-verified]
#pragma unroll
  for (int m = 0; m < 4; m++) {
    int row_base = row0 + wr * 64 + m * 16 + (lane >> 4) * 4;
#pragma unroll
    for (int nn = 0; nn < 4; nn++) {
      int col = col0 + wc * 64 + nn * 16 + (lane & 15);
#pragma unroll
      for (int j = 0; j < 4; j++) {
        int row = row_base + j;
        if (row < Mreal) C[(size_t)row * 256 + col] = acc[m][nn][j];
      }
    }
  }
}

// ---------------- alpha: per-row dots with a_src / a_dst ----------------
__global__ __launch_bounds__(256) void alpha_kernel(
    const float* __restrict__ h, const float* __restrict__ a_s,
    const float* __restrict__ a_d, float* __restrict__ alpha_s,
    float* __restrict__ alpha_d, int n) {
  int node = blockIdx.x * 4 + (threadIdx.x >> 6);
  int lane = threadIdx.x & 63;
  if (node >= n) return;
  float4 hv = ((const float4*)h)[(size_t)node * 64 + lane];
  float4 sv = ((const float4*)a_s)[lane];
  float4 dv = ((const float4*)a_d)[lane];
  float ps = hv.x * sv.x + hv.y * sv.y + hv.z * sv.z + hv.w * sv.w;
  float pd = hv.x * dv.x + hv.y * dv.y + hv.z * dv.z + hv.w * dv.w;
  ps = wave_sum(ps);
  pd = wave_sum(pd);
  if (lane == 0) {
    alpha_s[node] = ps;
    alpha_d[node] = pd;
  }
}

// ---------------- GAT attention + aggregation (wave per node) ----------------
__global__ __launch_bounds__(256) void gat_agg(
    const float* __restrict__ hw, const float* __restrict__ as_,
    const float* __restrict__ ad_, const int* __restrict__ row_off,
    const int* __restrict__ col_src, const float* __restrict__ bias,
    float* __restrict__ out, int n, int relu_out) {
  int node = blockIdx.x * 4 + (threadIdx.x >> 6);
  int lane = threadIdx.x & 63;
  if (node >= n) return;
  int lo = row_off[node], hi = row_off[node + 1];
  int deg = hi - lo;
  float adn = ad_[node];
  float self_e = leaky(as_[node] + adn);

  float m = self_e;
  for (int e = lane; e < deg; e += 64) {
    int s = col_src[lo + e];
    m = fmaxf(m, leaky(as_[s] + adn));
  }
  m = wave_max(m);

  float z = 0.f;
  for (int e = lane; e < deg; e += 64) {
    int s = col_src[lo + e];
    z += __expf(leaky(as_[s] + adn) - m);
  }
  z = wave_sum(z);
  float ez_self = __expf(self_e - m);
  z += ez_self;
  float inv_z = 1.0f / z;

  const float4* h4 = (const float4*)hw;
  float4 hv = h4[(size_t)node * 64 + lane];
  float ws = ez_self * inv_z;
  float4 acc = make_float4(hv.x * ws, hv.y * ws, hv.z * ws, hv.w * ws);
  for (int e = 0; e < deg; e++) {
    int s = col_src[lo + e];
    float wgt = __expf(leaky(as_[s] + adn) - m) * inv_z;
    float4 v = h4[(size_t)s * 64 + lane];
    acc.x = fmaf(wgt, v.x, acc.x);
    acc.y = fmaf(wgt, v.y, acc.y);
    acc.z = fmaf(wgt, v.z, acc.z);
    acc.w = fmaf(wgt, v.w, acc.w);
  }
  float4 bb = ((const float4*)bias)[lane];
  acc.x += bb.x; acc.y += bb.y; acc.z += bb.z; acc.w += bb.w;
  if (relu_out) {
    acc.x = fmaxf(acc.x, 0.f); acc.y = fmaxf(acc.y, 0.f);
    acc.z = fmaxf(acc.z, 0.f); acc.w = fmaxf(acc.w, 0.f);
  }
  ((float4*)out)[(size_t)node * 64 + lane] = acc;
}

// ---------------- BN stats ----------------
__global__ __launch_bounds__(256) void bn_stats(const float* __restrict__ h, int n,
                                                float* __restrict__ bsum,
                                                float* __restrict__ bsq) {
  int c = threadIdx.x;
  int rows_per_block = (n + gridDim.x - 1) / gridDim.x;
  int r0 = blockIdx.x * rows_per_block;
  int r1 = min(r0 + rows_per_block, n);
  float sum = 0.f, sq = 0.f;
  for (int r = r0; r < r1; r++) {
    float v = h[(size_t)r * 256 + c];
    sum += v;
    sq = fmaf(v, v, sq);
  }
  atomicAdd(&bsum[c], sum);
  atomicAdd(&bsq[c], sq);
}

// ---------------- BN apply + ReLU -> bf16 for GEMM2 ----------------
__global__ __launch_bounds__(256) void bn_apply(const float* __restrict__ h,
                                                const float* __restrict__ bsum,
                                                const float* __restrict__ bsq,
                                                const float* __restrict__ gamma,
                                                const float* __restrict__ beta,
                                                ushort_t* __restrict__ h2b, int n) {
  int total4 = n * 64;
  float inv_n = 1.0f / (float)n;
  for (int f = blockIdx.x * blockDim.x + threadIdx.x; f < total4;
       f += gridDim.x * blockDim.x) {
    int c4 = f & 63;
    float4 v = ((const float4*)h)[f];
    float4 sm = ((const float4*)bsum)[c4];
    float4 sl = ((const float4*)bsq)[c4];
    float4 g = ((const float4*)gamma)[c4];
    float4 bb = ((const float4*)beta)[c4];
    float m, var;
    m = sm.x * inv_n; var = sl.x * inv_n - m * m;
    v.x = fmaxf(g.x * (v.x - m) * rsqrtf(var + 1e-5f) + bb.x, 0.f);
    m = sm.y * inv_n; var = sl.y * inv_n - m * m;
    v.y = fmaxf(g.y * (v.y - m) * rsqrtf(var + 1e-5f) + bb.y, 0.f);
    m = sm.z * inv_n; var = sl.z * inv_n - m * m;
    v.z = fmaxf(g.z * (v.z - m) * rsqrtf(var + 1e-5f) + bb.z, 0.f);
    m = sm.w * inv_n; var = sl.w * inv_n - m * m;
    v.w = fmaxf(g.w * (v.w - m) * rsqrtf(var + 1e-5f) + bb.w, 0.f);
    *(ushort4*)&h2b[(size_t)f * 4] =
        make_ushort4(f2bf(v.x), f2bf(v.y), f2bf(v.z), f2bf(v.w));
  }
}

// ---------------- mean pool per graph ----------------
__device__ inline int lower_bound_dev(const int* a, int n, int v) {
  int lo = 0, hi = n;
  while (lo < hi) {
    int mid = (lo + hi) >> 1;
    if (a[mid] < v) lo = mid + 1; else hi = mid;
  }
  return lo;
}

__global__ __launch_bounds__(256) void pool_kernel(const float* __restrict__ h,
                                                   const int* __restrict__ batch, int n,
                                                   float* __restrict__ pooled) {
  int g = blockIdx.x;
  int lo = lower_bound_dev(batch, n, g);
  int hi = lower_bound_dev(batch, n, g + 1);
  float sum = 0.f;
  for (int r = lo; r < hi; r++) sum += h[(size_t)r * 256 + threadIdx.x];
  pooled[(size_t)g * 256 + threadIdx.x] = sum / fmaxf((float)(hi - lo), 1.0f);
}

// ---------------- final head ----------------
__global__ __launch_bounds__(256) void final_kernel(const float* __restrict__ pooled,
                                                    const float* __restrict__ ce,
                                                    const float* __restrict__ Wc,
                                                    const float* __restrict__ bc,
                                                    float* __restrict__ out, int B) {
  int g = blockIdx.x;
  int t = threadIdx.x;
  float p = 0.f;
  p = fmaf(pooled[(size_t)g * 256 + t], Wc[t], p);
  p = fmaf(ce[(size_t)g * 768 + t],        Wc[256 + t], p);
  p = fmaf(ce[(size_t)g * 768 + 256 + t],  Wc[512 + t], p);
  p = fmaf(ce[(size_t)g * 768 + 512 + t],  Wc[768 + t], p);
  __shared__ float red[256];
  red[t] = p;
  __syncthreads();
  for (int s = 128; s; s >>= 1) {
    if (t < s) red[t] += red[t + s];
    __syncthreads();
  }
  if (t == 0) out[g] = red[0] + bc[0];
}

// ---------------- launch ----------------
extern "C" void kernel_launch(void* const* d_in, const int* in_sizes, int n_in,
                              void* d_out, int out_size, void* d_ws, size_t ws_size,
                              hipStream_t stream) {
  const float* ce    = (const float*)d_in[0];
  const float* x     = (const float*)d_in[1];
  const int*   edge  = (const int*)d_in[2];
  const int*   batch = (const int*)d_in[3];
  const float* W1    = (const float*)d_in[4];
  const float* a_s1  = (const float*)d_in[5];
  const float* a_d1  = (const float*)d_in[6];
  const float* b1    = (const float*)d_in[7];
  const float* W2    = (const float*)d_in[8];
  const float* a_s2  = (const float*)d_in[9];
  const float* a_d2  = (const float*)d_in[10];
  const float* b2    = (const float*)d_in[11];
  const float* gamma = (const float*)d_in[12];
  const float* beta  = (const float*)d_in[13];
  const float* Wc    = (const float*)d_in[14];
  const float* bc    = (const float*)d_in[15];

  const int B = in_sizes[0] / DIN;
  const int n = in_sizes[1] / DIN;
  const int E = in_sizes[2] / 2;
  const int* esrc = edge;
  const int* edst = edge + E;

  char* w = (char*)d_ws;
  size_t off = 0;
  auto carve = [&](size_t bytes) -> void* {
    void* p = w + off;
    off = (off + bytes + 255) & ~(size_t)255;
    return p;
  };
  // R1 region: xb (layer-1 GEMM input) lives first; after GEMM1 it is dead and
  // the identical-size pair {buf_o, h2b} reuses the space (51.2MB + 25.6MB = 76.8MB).
  size_t xb_bytes   = (size_t)n * DIN * 2;       // 76.8 MB
  size_t bufo_bytes = (size_t)n * DH * 4;        // 51.2 MB
  char*  R1      = (char*)carve(xb_bytes);
  ushort_t* xb   = (ushort_t*)R1;
  float*    buf_o = (float*)R1;
  ushort_t* h2b  = (ushort_t*)(R1 + bufo_bytes); // 51.2MB offset, 256-aligned
  float* buf_h   = (float*)carve((size_t)n * DH * 4);
  int*   cnt     = (int*)carve((size_t)n * 4);
  int*   row_off = (int*)carve((size_t)(n + 1) * 4);
  int*   fill    = (int*)carve((size_t)n * 4);
  int*   col_src = (int*)carve((size_t)E * 4);
  float* alpha_s = (float*)carve((size_t)n * 4);
  float* alpha_d = (float*)carve((size_t)n * 4);
  float* bn_sum  = (float*)carve(DH * 4);
  float* bn_sq   = (float*)carve(DH * 4);
  float* pooled  = (float*)carve((size_t)B * DH * 4);
  ushort_t* Wt1  = (ushort_t*)carve((size_t)DIN * DH * 2);
  ushort_t* Wt2  = (ushort_t*)carve((size_t)DH * DH * 2);

  hipMemsetAsync(cnt, 0, (size_t)n * 4, stream);
  hipMemsetAsync(fill, 0, (size_t)n * 4, stream);
  hipMemsetAsync(bn_sum, 0, DH * 4, stream);
  hipMemsetAsync(bn_sq, 0, DH * 4, stream);

  const int gN4 = (n + 3) / 4;
  const int Mb = (n + 127) / 128;

  // weight prep + cosine gate + CSR build
  wt_kernel<<<(DIN + 255) / 256, 256, 0, stream>>>(W1, Wt1, DIN);
  wt_kernel<<<(DH + 255) / 256, 256, 0, stream>>>(W2, Wt2, DH);
  relxb_kernel<<<gN4, 256, 0, stream>>>(ce, x, batch, xb, n);
  hist_kernel<<<1024, 256, 0, stream>>>(edst, E, cnt);
  scan_kernel<<<1, 1024, 0, stream>>>(cnt, row_off, n);
  fill_kernel<<<1024, 256, 0, stream>>>(esrc, edst, E, row_off, fill, col_src);

  // ---- layer 1 ----
  gemm_mfma<DIN><<<dim3(Mb, 2), 256, 0, stream>>>(xb, Wt1, buf_h, n);
  alpha_kernel<<<gN4, 256, 0, stream>>>(buf_h, a_s1, a_d1, alpha_s, alpha_d, n);
  gat_agg<<<gN4, 256, 0, stream>>>(buf_h, alpha_s, alpha_d, row_off, col_src, b1,
                                   buf_o, n, 0);
  bn_stats<<<512, 256, 0, stream>>>(buf_o, n, bn_sum, bn_sq);
  bn_apply<<<2048, 256, 0, stream>>>(buf_o, bn_sum, bn_sq, gamma, beta, h2b, n);

  // ---- layer 2 ----
  gemm_mfma<DH><<<dim3(Mb, 2), 256, 0, stream>>>(h2b, Wt2, buf_h, n);
  alpha_kernel<<<gN4, 256, 0, stream>>>(buf_h, a_s2, a_d2, alpha_s, alpha_d, n);
  gat_agg<<<gN4, 256, 0, stream>>>(buf_h, alpha_s, alpha_d, row_off, col_src, b2,
                                   buf_o, n, 1);

  // ---- head ----
  pool_kernel<<<B, 256, 0, stream>>>(buf_o, batch, n, pooled);
  final_kernel<<<B, 256, 0, stream>>>(pooled, ce, Wc, bc, (float*)d_out, B);
}

// Round 3
// 637.728 us; speedup vs baseline: 1.5553x; 1.2204x over previous
//
#include <hip/hip_runtime.h>
#include <hip/hip_bf16.h>

#define DIN 768
#define DH  256

typedef unsigned short ushort_t;
typedef __attribute__((ext_vector_type(8))) short short8v;   // 8 bf16 (4 VGPRs)
typedef __attribute__((ext_vector_type(4))) float f32x4;

__device__ inline float wave_sum(float v) {
#pragma unroll
  for (int o = 32; o; o >>= 1) v += __shfl_xor(v, o);
  return v;
}
__device__ inline float wave_max(float v) {
#pragma unroll
  for (int o = 32; o; o >>= 1) v = fmaxf(v, __shfl_xor(v, o));
  return v;
}
__device__ inline float leaky(float v) { return v > 0.f ? v : 0.2f * v; }

__device__ inline ushort_t f2bf(float f) {
  union { float f; unsigned u; } v; v.f = f;
  unsigned r = v.u + 0x7FFFu + ((v.u >> 16) & 1u);  // RNE
  return (ushort_t)(r >> 16);
}

__device__ inline void unpack8(uint4 v, float* f) {
  union { unsigned u; float f; } t;
  t.u = v.x << 16;         f[0] = t.f;
  t.u = v.x & 0xFFFF0000u; f[1] = t.f;
  t.u = v.y << 16;         f[2] = t.f;
  t.u = v.y & 0xFFFF0000u; f[3] = t.f;
  t.u = v.z << 16;         f[4] = t.f;
  t.u = v.z & 0xFFFF0000u; f[5] = t.f;
  t.u = v.w << 16;         f[6] = t.f;
  t.u = v.w & 0xFFFF0000u; f[7] = t.f;
}

// ---------------- K1: cosine relevance gating + bf16(x*rel) ----------------
__global__ __launch_bounds__(256) void relxb_kernel(
    const float* __restrict__ ce, const float* __restrict__ x,
    const int* __restrict__ batch, ushort_t* __restrict__ xb, int n) {
  int node = blockIdx.x * 4 + (threadIdx.x >> 6);
  int lane = threadIdx.x & 63;
  if (node >= n) return;
  int g = batch[node];
  const float4* xr = (const float4*)(x + (size_t)node * DIN);
  const float4* cr = (const float4*)(ce + (size_t)g * DIN);
  float4 av[3];
  float dxy = 0.f, dxx = 0.f, dcc = 0.f;
#pragma unroll
  for (int i = 0; i < 3; i++) {
    float4 a = xr[lane + 64 * i];
    float4 b = cr[lane + 64 * i];
    av[i] = a;
    dxy += a.x*b.x + a.y*b.y + a.z*b.z + a.w*b.w;
    dxx += a.x*a.x + a.y*a.y + a.z*a.z + a.w*a.w;
    dcc += b.x*b.x + b.y*b.y + b.z*b.z + b.w*b.w;
  }
  dxy = wave_sum(dxy);
  dxx = wave_sum(dxx);
  dcc = wave_sum(dcc);
  float denom = fmaxf(sqrtf(dxx) * sqrtf(dcc), 1e-8f);
  float rel = dxy / denom;
#pragma unroll
  for (int i = 0; i < 3; i++) {
    float4 a = av[i];
    ushort4 o = make_ushort4(f2bf(a.x * rel), f2bf(a.y * rel),
                             f2bf(a.z * rel), f2bf(a.w * rel));
    *(ushort4*)&xb[(size_t)node * DIN + (lane + 64 * i) * 4] = o;
  }
}

// ---------------- W transpose + bf16 cast: W[K][256] -> Wt[256][K] ----------------
__global__ void wt_kernel(const float* __restrict__ W, ushort_t* __restrict__ Wt, int K) {
  int k = blockIdx.x * 256 + threadIdx.x;
  if (k >= K) return;
  for (int c = 0; c < 256; c++)
    Wt[(size_t)c * K + k] = f2bf(W[(size_t)k * 256 + c]);
}

// ---------------- CSR build ----------------
__global__ void hist_kernel(const int* __restrict__ dst, int E, int* __restrict__ cnt) {
  for (int e = blockIdx.x * blockDim.x + threadIdx.x; e < E; e += gridDim.x * blockDim.x)
    atomicAdd(&cnt[dst[e]], 1);
}

__global__ __launch_bounds__(1024) void scan_kernel(const int* __restrict__ cnt,
                                                    int* __restrict__ row_off, int n) {
  __shared__ int s[1024];
  int t = threadIdx.x;
  int chunk = (n + 1023) / 1024;
  int lo = t * chunk, hi = min(lo + chunk, n);
  int sum = 0;
  for (int i = lo; i < hi; i++) sum += cnt[i];
  int mysum = sum;
  s[t] = sum;
  __syncthreads();
  for (int off = 1; off < 1024; off <<= 1) {
    int v = (t >= off) ? s[t - off] : 0;
    __syncthreads();
    s[t] += v;
    __syncthreads();
  }
  int run = s[t] - mysum;
  for (int i = lo; i < hi; i++) { row_off[i] = run; run += cnt[i]; }
  if (t == 1023) row_off[n] = s[1023];
}

__global__ void fill_kernel(const int* __restrict__ src, const int* __restrict__ dst, int E,
                            const int* __restrict__ row_off, int* __restrict__ fill,
                            int* __restrict__ col_src) {
  for (int e = blockIdx.x * blockDim.x + threadIdx.x; e < E; e += gridDim.x * blockDim.x) {
    int d = dst[e];
    int slot = row_off[d] + atomicAdd(&fill[d], 1);
    col_src[slot] = src[e];
  }
}

// ---------------- bf16 MFMA GEMM: C[M,256](bf16) = A[M,K] @ Bt[256,K]^T ----------------
template <int K>
__global__ __launch_bounds__(256) void gemm_mfma(
    const ushort_t* __restrict__ A, const ushort_t* __restrict__ Bt,
    ushort_t* __restrict__ C, int Mreal) {
  __shared__ ushort_t lds[16384];  // A: [0,8192) shorts, B: [8192,16384)
  const int tid = threadIdx.x;
  const int lane = tid & 63;
  const int wave = tid >> 6;
  const int row0 = blockIdx.x * 128;
  const int col0 = blockIdx.y * 128;
  const int wr = wave >> 1, wc = wave & 1;

  f32x4 acc[4][4];
#pragma unroll
  for (int m = 0; m < 4; m++)
#pragma unroll
    for (int nn = 0; nn < 4; nn++)
#pragma unroll
      for (int j = 0; j < 4; j++) acc[m][nn][j] = 0.f;

  for (int k0 = 0; k0 < K; k0 += 64) {
#pragma unroll
    for (int c = 0; c < 8; c++) {
      int chunk = wave * 8 + c;
      int isB = chunk >> 4;
      int i = chunk & 15;
      int kb = i >> 1, half = i & 1;
      int ldsbase = isB * 8192 + kb * 1024 + half * 512;
      const ushort_t* gsrc;
      int grow = half * 64 + lane;
      if (isB == 0) {
        int r = row0 + grow;
        r = r < Mreal ? r : Mreal - 1;
        gsrc = A + (size_t)r * K + k0 + kb * 8;
      } else {
        gsrc = Bt + (size_t)(col0 + grow) * K + k0 + kb * 8;
      }
      __builtin_amdgcn_global_load_lds(
          (const __attribute__((address_space(1))) void*)gsrc,
          (__attribute__((address_space(3))) void*)&lds[ldsbase], 16, 0, 0);
    }
    __syncthreads();
#pragma unroll
    for (int ks = 0; ks < 2; ks++) {
      short8v a[4], b[4];
#pragma unroll
      for (int m = 0; m < 4; m++) {
        int idx = (ks * 4 + (lane >> 4)) * 1024 + (wr * 64 + m * 16 + (lane & 15)) * 8;
        a[m] = *(const short8v*)&lds[idx];
      }
#pragma unroll
      for (int nn = 0; nn < 4; nn++) {
        int idx = 8192 + (ks * 4 + (lane >> 4)) * 1024 +
                  (wc * 64 + nn * 16 + (lane & 15)) * 8;
        b[nn] = *(const short8v*)&lds[idx];
      }
#pragma unroll
      for (int m = 0; m < 4; m++)
#pragma unroll
        for (int nn = 0; nn < 4; nn++)
          acc[m][nn] = __builtin_amdgcn_mfma_f32_16x16x32_bf16(a[m], b[nn],
                                                               acc[m][nn], 0, 0, 0);
    }
    __syncthreads();
  }
#pragma unroll
  for (int m = 0; m < 4; m++) {
    int row_base = row0 + wr * 64 + m * 16 + (lane >> 4) * 4;
#pragma unroll
    for (int nn = 0; nn < 4; nn++) {
      int col = col0 + wc * 64 + nn * 16 + (lane & 15);
#pragma unroll
      for (int j = 0; j < 4; j++) {
        int row = row_base + j;
        if (row < Mreal) C[(size_t)row * 256 + col] = f2bf(acc[m][nn][j]);
      }
    }
  }
}

// ---------------- alpha: per-row dots with a_src / a_dst (bf16 h) ----------------
__global__ __launch_bounds__(256) void alpha_kernel(
    const ushort_t* __restrict__ hb, const float* __restrict__ a_s,
    const float* __restrict__ a_d, float* __restrict__ alpha_s,
    float* __restrict__ alpha_d, int n) {
  int node = blockIdx.x * 4 + (threadIdx.x >> 6);
  int lane = threadIdx.x & 63;
  if (node >= n) return;
  uint2 hv = ((const uint2*)(hb + (size_t)node * 256))[lane];
  float f[4];
  union { unsigned u; float fl; } t;
  t.u = hv.x << 16;         f[0] = t.fl;
  t.u = hv.x & 0xFFFF0000u; f[1] = t.fl;
  t.u = hv.y << 16;         f[2] = t.fl;
  t.u = hv.y & 0xFFFF0000u; f[3] = t.fl;
  float4 sv = ((const float4*)a_s)[lane];
  float4 dv = ((const float4*)a_d)[lane];
  float ps = f[0]*sv.x + f[1]*sv.y + f[2]*sv.z + f[3]*sv.w;
  float pd = f[0]*dv.x + f[1]*dv.y + f[2]*dv.z + f[3]*dv.w;
  ps = wave_sum(ps);
  pd = wave_sum(pd);
  if (lane == 0) {
    alpha_s[node] = ps;
    alpha_d[node] = pd;
  }
}

// ---------------- GAT attention + aggregation (wave per node, bf16 gather) --------
// Phase A/B: per-lane edge registers (single gather of as[s]/col_src).
// Phase C: 2 edges per iteration — lanes 0..31 edge e, lanes 32..63 edge e+1,
// each lane loads 16B (8 bf16 cols), halves combined by shfl_xor(32).
__global__ __launch_bounds__(256) void gat_agg(
    const ushort_t* __restrict__ hb, const float* __restrict__ as_,
    const float* __restrict__ ad_, const int* __restrict__ row_off,
    const int* __restrict__ col_src, const float* __restrict__ bias,
    float* __restrict__ out, int n, int relu_out) {
  int node = blockIdx.x * 4 + (threadIdx.x >> 6);
  int lane = threadIdx.x & 63;
  if (node >= n) return;
  int lo = row_off[node], hi = row_off[node + 1];
  int deg = hi - lo;
  float adn = ad_[node];
  float self_e = leaky(as_[node] + adn);

  int cnt0 = min(deg, 64);
  int s0 = 0; float le0 = -3e38f;
  if (lane < cnt0) { s0 = col_src[lo + lane]; le0 = leaky(as_[s0] + adn); }

  // phase A: max
  float m = fmaxf(self_e, wave_max(le0));
  for (int base = 64; base < deg; base += 64) {
    int cnt = min(64, deg - base);
    float l2 = -3e38f;
    if (lane < cnt) l2 = leaky(as_[col_src[lo + base + lane]] + adn);
    m = fmaxf(m, wave_max(l2));
  }

  // phase B: sum of exp
  float z = wave_sum(lane < cnt0 ? __expf(le0 - m) : 0.f);
  for (int base = 64; base < deg; base += 64) {
    int cnt = min(64, deg - base);
    float ez = 0.f;
    if (lane < cnt) ez = __expf(leaky(as_[col_src[lo + base + lane]] + adn) - m);
    z += wave_sum(ez);
  }
  float ez_self = __expf(self_e - m);
  z += ez_self;
  float inv_z = 1.0f / z;

  // phase C: paired gather
  const int half = lane >> 5;
  const int l16 = lane & 31;
  float acc[8];
  {
    uint4 v = ((const uint4*)(hb + (size_t)node * 256))[l16];
    float f[8]; unpack8(v, f);
    float ws = (half == 0) ? ez_self * inv_z : 0.f;
#pragma unroll
    for (int i = 0; i < 8; i++) acc[i] = ws * f[i];
  }

  auto gather = [&](int sreg, float lereg, int cnt) {
    for (int e = 0; e < cnt; e += 2) {
      int myE = e + half;
      int idx = myE < cnt ? myE : cnt - 1;
      int ss = __shfl(sreg, idx);
      float lee = __shfl(lereg, idx);
      float wgt = (myE < cnt) ? __expf(lee - m) * inv_z : 0.f;
      uint4 v = ((const uint4*)(hb + (size_t)ss * 256))[l16];
      float f[8]; unpack8(v, f);
#pragma unroll
      for (int i = 0; i < 8; i++) acc[i] = fmaf(wgt, f[i], acc[i]);
    }
  };
  gather(s0, le0, cnt0);
  for (int base = 64; base < deg; base += 64) {
    int cnt = min(64, deg - base);
    int s2 = 0; float le2 = -3e38f;
    if (lane < cnt) { s2 = col_src[lo + base + lane]; le2 = leaky(as_[s2] + adn); }
    gather(s2, le2, cnt);
  }

#pragma unroll
  for (int i = 0; i < 8; i++) acc[i] += __shfl_xor(acc[i], 32);

  if (half == 0) {
    float4 b0 = *(const float4*)&bias[l16 * 8];
    float4 b1 = *(const float4*)&bias[l16 * 8 + 4];
    float o[8] = {acc[0]+b0.x, acc[1]+b0.y, acc[2]+b0.z, acc[3]+b0.w,
                  acc[4]+b1.x, acc[5]+b1.y, acc[6]+b1.z, acc[7]+b1.w};
    if (relu_out) {
#pragma unroll
      for (int i = 0; i < 8; i++) o[i] = fmaxf(o[i], 0.f);
    }
    *(float4*)&out[(size_t)node * 256 + l16 * 8]     = make_float4(o[0],o[1],o[2],o[3]);
    *(float4*)&out[(size_t)node * 256 + l16 * 8 + 4] = make_float4(o[4],o[5],o[6],o[7]);
  }
}

// ---------------- BN stats ----------------
__global__ __launch_bounds__(256) void bn_stats(const float* __restrict__ h, int n,
                                                float* __restrict__ bsum,
                                                float* __restrict__ bsq) {
  int c = threadIdx.x;
  int rows_per_block = (n + gridDim.x - 1) / gridDim.x;
  int r0 = blockIdx.x * rows_per_block;
  int r1 = min(r0 + rows_per_block, n);
  float sum = 0.f, sq = 0.f;
  for (int r = r0; r < r1; r++) {
    float v = h[(size_t)r * 256 + c];
    sum += v;
    sq = fmaf(v, v, sq);
  }
  atomicAdd(&bsum[c], sum);
  atomicAdd(&bsq[c], sq);
}

// ---------------- BN apply + ReLU -> bf16 for GEMM2 ----------------
__global__ __launch_bounds__(256) void bn_apply(const float* __restrict__ h,
                                                const float* __restrict__ bsum,
                                                const float* __restrict__ bsq,
                                                const float* __restrict__ gamma,
                                                const float* __restrict__ beta,
                                                ushort_t* __restrict__ h2b, int n) {
  int total4 = n * 64;
  float inv_n = 1.0f / (float)n;
  for (int f = blockIdx.x * blockDim.x + threadIdx.x; f < total4;
       f += gridDim.x * blockDim.x) {
    int c4 = f & 63;
    float4 v = ((const float4*)h)[f];
    float4 sm = ((const float4*)bsum)[c4];
    float4 sl = ((const float4*)bsq)[c4];
    float4 g = ((const float4*)gamma)[c4];
    float4 bb = ((const float4*)beta)[c4];
    float m, var;
    m = sm.x * inv_n; var = sl.x * inv_n - m * m;
    v.x = fmaxf(g.x * (v.x - m) * rsqrtf(var + 1e-5f) + bb.x, 0.f);
    m = sm.y * inv_n; var = sl.y * inv_n - m * m;
    v.y = fmaxf(g.y * (v.y - m) * rsqrtf(var + 1e-5f) + bb.y, 0.f);
    m = sm.z * inv_n; var = sl.z * inv_n - m * m;
    v.z = fmaxf(g.z * (v.z - m) * rsqrtf(var + 1e-5f) + bb.z, 0.f);
    m = sm.w * inv_n; var = sl.w * inv_n - m * m;
    v.w = fmaxf(g.w * (v.w - m) * rsqrtf(var + 1e-5f) + bb.w, 0.f);
    *(ushort4*)&h2b[(size_t)f * 4] =
        make_ushort4(f2bf(v.x), f2bf(v.y), f2bf(v.z), f2bf(v.w));
  }
}

// ---------------- mean pool per graph ----------------
__device__ inline int lower_bound_dev(const int* a, int n, int v) {
  int lo = 0, hi = n;
  while (lo < hi) {
    int mid = (lo + hi) >> 1;
    if (a[mid] < v) lo = mid + 1; else hi = mid;
  }
  return lo;
}

__global__ __launch_bounds__(256) void pool_kernel(const float* __restrict__ h,
                                                   const int* __restrict__ batch, int n,
                                                   float* __restrict__ pooled) {
  int g = blockIdx.x;
  int lo = lower_bound_dev(batch, n, g);
  int hi = lower_bound_dev(batch, n, g + 1);
  float sum = 0.f;
  for (int r = lo; r < hi; r++) sum += h[(size_t)r * 256 + threadIdx.x];
  pooled[(size_t)g * 256 + threadIdx.x] = sum / fmaxf((float)(hi - lo), 1.0f);
}

// ---------------- final head ----------------
__global__ __launch_bounds__(256) void final_kernel(const float* __restrict__ pooled,
                                                    const float* __restrict__ ce,
                                                    const float* __restrict__ Wc,
                                                    const float* __restrict__ bc,
                                                    float* __restrict__ out, int B) {
  int g = blockIdx.x;
  int t = threadIdx.x;
  float p = 0.f;
  p = fmaf(pooled[(size_t)g * 256 + t], Wc[t], p);
  p = fmaf(ce[(size_t)g * 768 + t],        Wc[256 + t], p);
  p = fmaf(ce[(size_t)g * 768 + 256 + t],  Wc[512 + t], p);
  p = fmaf(ce[(size_t)g * 768 + 512 + t],  Wc[768 + t], p);
  __shared__ float red[256];
  red[t] = p;
  __syncthreads();
  for (int s = 128; s; s >>= 1) {
    if (t < s) red[t] += red[t + s];
    __syncthreads();
  }
  if (t == 0) out[g] = red[0] + bc[0];
}

// ---------------- launch ----------------
extern "C" void kernel_launch(void* const* d_in, const int* in_sizes, int n_in,
                              void* d_out, int out_size, void* d_ws, size_t ws_size,
                              hipStream_t stream) {
  const float* ce    = (const float*)d_in[0];
  const float* x     = (const float*)d_in[1];
  const int*   edge  = (const int*)d_in[2];
  const int*   batch = (const int*)d_in[3];
  const float* W1    = (const float*)d_in[4];
  const float* a_s1  = (const float*)d_in[5];
  const float* a_d1  = (const float*)d_in[6];
  const float* b1    = (const float*)d_in[7];
  const float* W2    = (const float*)d_in[8];
  const float* a_s2  = (const float*)d_in[9];
  const float* a_d2  = (const float*)d_in[10];
  const float* b2    = (const float*)d_in[11];
  const float* gamma = (const float*)d_in[12];
  const float* beta  = (const float*)d_in[13];
  const float* Wc    = (const float*)d_in[14];
  const float* bc    = (const float*)d_in[15];

  const int B = in_sizes[0] / DIN;
  const int n = in_sizes[1] / DIN;
  const int E = in_sizes[2] / 2;
  const int* esrc = edge;
  const int* edst = edge + E;

  char* w = (char*)d_ws;
  size_t off = 0;
  auto carve = [&](size_t bytes) -> void* {
    void* p = w + off;
    off = (off + bytes + 255) & ~(size_t)255;
    return p;
  };
  // R1 region: xb (76.8MB) lives first; dead after GEMM1, then reused as
  // buf_o (51.2MB fp32) + h2b (25.6MB bf16).
  size_t xb_bytes   = (size_t)n * DIN * 2;
  size_t bufo_bytes = (size_t)n * DH * 4;
  char*  R1       = (char*)carve(xb_bytes);
  ushort_t* xb    = (ushort_t*)R1;
  float*    buf_o = (float*)R1;
  ushort_t* h2b   = (ushort_t*)(R1 + bufo_bytes);
  ushort_t* buf_hb = (ushort_t*)carve((size_t)n * DH * 2);  // bf16 h (GEMM out)
  int*   cnt     = (int*)carve((size_t)n * 4);
  int*   row_off = (int*)carve((size_t)(n + 1) * 4);
  int*   fill    = (int*)carve((size_t)n * 4);
  int*   col_src = (int*)carve((size_t)E * 4);
  float* alpha_s = (float*)carve((size_t)n * 4);
  float* alpha_d = (float*)carve((size_t)n * 4);
  float* bn_sum  = (float*)carve(DH * 4);
  float* bn_sq   = (float*)carve(DH * 4);
  float* pooled  = (float*)carve((size_t)B * DH * 4);
  ushort_t* Wt1  = (ushort_t*)carve((size_t)DIN * DH * 2);
  ushort_t* Wt2  = (ushort_t*)carve((size_t)DH * DH * 2);

  hipMemsetAsync(cnt, 0, (size_t)n * 4, stream);
  hipMemsetAsync(fill, 0, (size_t)n * 4, stream);
  hipMemsetAsync(bn_sum, 0, DH * 4, stream);
  hipMemsetAsync(bn_sq, 0, DH * 4, stream);

  const int gN4 = (n + 3) / 4;
  const int Mb = (n + 127) / 128;

  wt_kernel<<<(DIN + 255) / 256, 256, 0, stream>>>(W1, Wt1, DIN);
  wt_kernel<<<(DH + 255) / 256, 256, 0, stream>>>(W2, Wt2, DH);
  relxb_kernel<<<gN4, 256, 0, stream>>>(ce, x, batch, xb, n);
  hist_kernel<<<1024, 256, 0, stream>>>(edst, E, cnt);
  scan_kernel<<<1, 1024, 0, stream>>>(cnt, row_off, n);
  fill_kernel<<<1024, 256, 0, stream>>>(esrc, edst, E, row_off, fill, col_src);

  // ---- layer 1 ----
  gemm_mfma<DIN><<<dim3(Mb, 2), 256, 0, stream>>>(xb, Wt1, buf_hb, n);
  alpha_kernel<<<gN4, 256, 0, stream>>>(buf_hb, a_s1, a_d1, alpha_s, alpha_d, n);
  gat_agg<<<gN4, 256, 0, stream>>>(buf_hb, alpha_s, alpha_d, row_off, col_src, b1,
                                   buf_o, n, 0);
  bn_stats<<<512, 256, 0, stream>>>(buf_o, n, bn_sum, bn_sq);
  bn_apply<<<2048, 256, 0, stream>>>(buf_o, bn_sum, bn_sq, gamma, beta, h2b, n);

  // ---- layer 2 ----
  gemm_mfma<DH><<<dim3(Mb, 2), 256, 0, stream>>>(h2b, Wt2, buf_hb, n);
  alpha_kernel<<<gN4, 256, 0, stream>>>(buf_hb, a_s2, a_d2, alpha_s, alpha_d, n);
  gat_agg<<<gN4, 256, 0, stream>>>(buf_hb, alpha_s, alpha_d, row_off, col_src, b2,
                                   buf_o, n, 1);

  // ---- head ----
  pool_kernel<<<B, 256, 0, stream>>>(buf_o, batch, n, pooled);
  final_kernel<<<B, 256, 0, stream>>>(pooled, ce, Wc, bc, (float*)d_out, B);
}

// Round 4
// 559.831 us; speedup vs baseline: 1.7717x; 1.1391x over previous
//
#include <hip/hip_runtime.h>
#include <hip/hip_bf16.h>

#define DIN 768
#define DH  256

typedef unsigned short ushort_t;
typedef __attribute__((ext_vector_type(8))) short short8v;   // 8 bf16 (4 VGPRs)
typedef __attribute__((ext_vector_type(4))) float f32x4;

__device__ inline float wave_sum(float v) {
#pragma unroll
  for (int o = 32; o; o >>= 1) v += __shfl_xor(v, o);
  return v;
}
__device__ inline float wave_max(float v) {
#pragma unroll
  for (int o = 32; o; o >>= 1) v = fmaxf(v, __shfl_xor(v, o));
  return v;
}
__device__ inline float leaky(float v) { return v > 0.f ? v : 0.2f * v; }

__device__ inline ushort_t f2bf(float f) {
  union { float f; unsigned u; } v; v.f = f;
  unsigned r = v.u + 0x7FFFu + ((v.u >> 16) & 1u);  // RNE
  return (ushort_t)(r >> 16);
}

__device__ inline void unpack8(uint4 v, float* f) {
  union { unsigned u; float f; } t;
  t.u = v.x << 16;         f[0] = t.f;
  t.u = v.x & 0xFFFF0000u; f[1] = t.f;
  t.u = v.y << 16;         f[2] = t.f;
  t.u = v.y & 0xFFFF0000u; f[3] = t.f;
  t.u = v.z << 16;         f[4] = t.f;
  t.u = v.z & 0xFFFF0000u; f[5] = t.f;
  t.u = v.w << 16;         f[6] = t.f;
  t.u = v.w & 0xFFFF0000u; f[7] = t.f;
}

// ---------------- K1: cosine relevance gating + bf16(x*rel) ----------------
__global__ __launch_bounds__(256) void relxb_kernel(
    const float* __restrict__ ce, const float* __restrict__ x,
    const int* __restrict__ batch, ushort_t* __restrict__ xb, int n) {
  int node = blockIdx.x * 4 + (threadIdx.x >> 6);
  int lane = threadIdx.x & 63;
  if (node >= n) return;
  int g = batch[node];
  const float4* xr = (const float4*)(x + (size_t)node * DIN);
  const float4* cr = (const float4*)(ce + (size_t)g * DIN);
  float4 av[3];
  float dxy = 0.f, dxx = 0.f, dcc = 0.f;
#pragma unroll
  for (int i = 0; i < 3; i++) {
    float4 a = xr[lane + 64 * i];
    float4 b = cr[lane + 64 * i];
    av[i] = a;
    dxy += a.x*b.x + a.y*b.y + a.z*b.z + a.w*b.w;
    dxx += a.x*a.x + a.y*a.y + a.z*a.z + a.w*a.w;
    dcc += b.x*b.x + b.y*b.y + b.z*b.z + b.w*b.w;
  }
  dxy = wave_sum(dxy);
  dxx = wave_sum(dxx);
  dcc = wave_sum(dcc);
  float denom = fmaxf(sqrtf(dxx) * sqrtf(dcc), 1e-8f);
  float rel = dxy / denom;
#pragma unroll
  for (int i = 0; i < 3; i++) {
    float4 a = av[i];
    ushort4 o = make_ushort4(f2bf(a.x * rel), f2bf(a.y * rel),
                             f2bf(a.z * rel), f2bf(a.w * rel));
    *(ushort4*)&xb[(size_t)node * DIN + (lane + 64 * i) * 4] = o;
  }
}

// ---------------- W transpose + bf16 cast: W[K][256] -> Wt[256][K] ----------------
__global__ void wt_kernel(const float* __restrict__ W, ushort_t* __restrict__ Wt, int K) {
  int k = blockIdx.x * 256 + threadIdx.x;
  if (k >= K) return;
  for (int c = 0; c < 256; c++)
    Wt[(size_t)c * K + k] = f2bf(W[(size_t)k * 256 + c]);
}

// ---------------- CSR build ----------------
__global__ void hist_kernel(const int* __restrict__ dst, int E, int* __restrict__ cnt) {
  for (int e = blockIdx.x * blockDim.x + threadIdx.x; e < E; e += gridDim.x * blockDim.x)
    atomicAdd(&cnt[dst[e]], 1);
}

__global__ __launch_bounds__(1024) void scan_kernel(const int* __restrict__ cnt,
                                                    int* __restrict__ row_off, int n) {
  __shared__ int s[1024];
  int t = threadIdx.x;
  int chunk = (n + 1023) / 1024;
  int lo = t * chunk, hi = min(lo + chunk, n);
  int sum = 0;
  for (int i = lo; i < hi; i++) sum += cnt[i];
  int mysum = sum;
  s[t] = sum;
  __syncthreads();
  for (int off = 1; off < 1024; off <<= 1) {
    int v = (t >= off) ? s[t - off] : 0;
    __syncthreads();
    s[t] += v;
    __syncthreads();
  }
  int run = s[t] - mysum;
  for (int i = lo; i < hi; i++) { row_off[i] = run; run += cnt[i]; }
  if (t == 1023) row_off[n] = s[1023];
}

__global__ void fill_kernel(const int* __restrict__ src, const int* __restrict__ dst, int E,
                            const int* __restrict__ row_off, int* __restrict__ fill,
                            int* __restrict__ col_src) {
  for (int e = blockIdx.x * blockDim.x + threadIdx.x; e < E; e += gridDim.x * blockDim.x) {
    int d = dst[e];
    int slot = row_off[d] + atomicAdd(&fill[d], 1);
    col_src[slot] = src[e];
  }
}

// ---------------- bf16 MFMA GEMM: C[M,256](bf16) = A[M,K] @ Bt[256,K]^T ----------------
template <int K>
__global__ __launch_bounds__(256) void gemm_mfma(
    const ushort_t* __restrict__ A, const ushort_t* __restrict__ Bt,
    ushort_t* __restrict__ C, int Mreal) {
  __shared__ ushort_t lds[16384];  // A: [0,8192) shorts, B: [8192,16384)
  const int tid = threadIdx.x;
  const int lane = tid & 63;
  const int wave = tid >> 6;
  const int row0 = blockIdx.x * 128;
  const int col0 = blockIdx.y * 128;
  const int wr = wave >> 1, wc = wave & 1;

  f32x4 acc[4][4];
#pragma unroll
  for (int m = 0; m < 4; m++)
#pragma unroll
    for (int nn = 0; nn < 4; nn++)
#pragma unroll
      for (int j = 0; j < 4; j++) acc[m][nn][j] = 0.f;

  for (int k0 = 0; k0 < K; k0 += 64) {
#pragma unroll
    for (int c = 0; c < 8; c++) {
      int chunk = wave * 8 + c;
      int isB = chunk >> 4;
      int i = chunk & 15;
      int kb = i >> 1, half = i & 1;
      int ldsbase = isB * 8192 + kb * 1024 + half * 512;
      const ushort_t* gsrc;
      int grow = half * 64 + lane;
      if (isB == 0) {
        int r = row0 + grow;
        r = r < Mreal ? r : Mreal - 1;
        gsrc = A + (size_t)r * K + k0 + kb * 8;
      } else {
        gsrc = Bt + (size_t)(col0 + grow) * K + k0 + kb * 8;
      }
      __builtin_amdgcn_global_load_lds(
          (const __attribute__((address_space(1))) void*)gsrc,
          (__attribute__((address_space(3))) void*)&lds[ldsbase], 16, 0, 0);
    }
    __syncthreads();
#pragma unroll
    for (int ks = 0; ks < 2; ks++) {
      short8v a[4], b[4];
#pragma unroll
      for (int m = 0; m < 4; m++) {
        int idx = (ks * 4 + (lane >> 4)) * 1024 + (wr * 64 + m * 16 + (lane & 15)) * 8;
        a[m] = *(const short8v*)&lds[idx];
      }
#pragma unroll
      for (int nn = 0; nn < 4; nn++) {
        int idx = 8192 + (ks * 4 + (lane >> 4)) * 1024 +
                  (wc * 64 + nn * 16 + (lane & 15)) * 8;
        b[nn] = *(const short8v*)&lds[idx];
      }
#pragma unroll
      for (int m = 0; m < 4; m++)
#pragma unroll
        for (int nn = 0; nn < 4; nn++)
          acc[m][nn] = __builtin_amdgcn_mfma_f32_16x16x32_bf16(a[m], b[nn],
                                                               acc[m][nn], 0, 0, 0);
    }
    __syncthreads();
  }
#pragma unroll
  for (int m = 0; m < 4; m++) {
    int row_base = row0 + wr * 64 + m * 16 + (lane >> 4) * 4;
#pragma unroll
    for (int nn = 0; nn < 4; nn++) {
      int col = col0 + wc * 64 + nn * 16 + (lane & 15);
#pragma unroll
      for (int j = 0; j < 4; j++) {
        int row = row_base + j;
        if (row < Mreal) C[(size_t)row * 256 + col] = f2bf(acc[m][nn][j]);
      }
    }
  }
}

// ---------------- alpha: per-row dots with a_src / a_dst (bf16 h) ----------------
__global__ __launch_bounds__(256) void alpha_kernel(
    const ushort_t* __restrict__ hb, const float* __restrict__ a_s,
    const float* __restrict__ a_d, float* __restrict__ alpha_s,
    float* __restrict__ alpha_d, int n) {
  int node = blockIdx.x * 4 + (threadIdx.x >> 6);
  int lane = threadIdx.x & 63;
  if (node >= n) return;
  uint2 hv = ((const uint2*)(hb + (size_t)node * 256))[lane];
  float f[4];
  union { unsigned u; float fl; } t;
  t.u = hv.x << 16;         f[0] = t.fl;
  t.u = hv.x & 0xFFFF0000u; f[1] = t.fl;
  t.u = hv.y << 16;         f[2] = t.fl;
  t.u = hv.y & 0xFFFF0000u; f[3] = t.fl;
  float4 sv = ((const float4*)a_s)[lane];
  float4 dv = ((const float4*)a_d)[lane];
  float ps = f[0]*sv.x + f[1]*sv.y + f[2]*sv.z + f[3]*sv.w;
  float pd = f[0]*dv.x + f[1]*dv.y + f[2]*dv.z + f[3]*dv.w;
  ps = wave_sum(ps);
  pd = wave_sum(pd);
  if (lane == 0) {
    alpha_s[node] = ps;
    alpha_d[node] = pd;
  }
}

// ---------------- GAT attention + aggregation (wave per node, bf16 gather) --------
__global__ __launch_bounds__(256) void gat_agg(
    const ushort_t* __restrict__ hb, const float* __restrict__ as_,
    const float* __restrict__ ad_, const int* __restrict__ row_off,
    const int* __restrict__ col_src, const float* __restrict__ bias,
    float* __restrict__ out, int n, int relu_out) {
  int node = blockIdx.x * 4 + (threadIdx.x >> 6);
  int lane = threadIdx.x & 63;
  if (node >= n) return;
  int lo = row_off[node], hi = row_off[node + 1];
  int deg = hi - lo;
  float adn = ad_[node];
  float self_e = leaky(as_[node] + adn);

  int cnt0 = min(deg, 64);
  int s0 = 0; float le0 = -3e38f;
  if (lane < cnt0) { s0 = col_src[lo + lane]; le0 = leaky(as_[s0] + adn); }

  // phase A: max
  float m = fmaxf(self_e, wave_max(le0));
  for (int base = 64; base < deg; base += 64) {
    int cnt = min(64, deg - base);
    float l2 = -3e38f;
    if (lane < cnt) l2 = leaky(as_[col_src[lo + base + lane]] + adn);
    m = fmaxf(m, wave_max(l2));
  }

  // phase B: sum of exp
  float z = wave_sum(lane < cnt0 ? __expf(le0 - m) : 0.f);
  for (int base = 64; base < deg; base += 64) {
    int cnt = min(64, deg - base);
    float ez = 0.f;
    if (lane < cnt) ez = __expf(leaky(as_[col_src[lo + base + lane]] + adn) - m);
    z += wave_sum(ez);
  }
  float ez_self = __expf(self_e - m);
  z += ez_self;
  float inv_z = 1.0f / z;

  // phase C: paired gather
  const int half = lane >> 5;
  const int l16 = lane & 31;
  float acc[8];
  {
    uint4 v = ((const uint4*)(hb + (size_t)node * 256))[l16];
    float f[8]; unpack8(v, f);
    float ws = (half == 0) ? ez_self * inv_z : 0.f;
#pragma unroll
    for (int i = 0; i < 8; i++) acc[i] = ws * f[i];
  }

  auto gather = [&](int sreg, float lereg, int cnt) {
    for (int e = 0; e < cnt; e += 2) {
      int myE = e + half;
      int idx = myE < cnt ? myE : cnt - 1;
      int ss = __shfl(sreg, idx);
      float lee = __shfl(lereg, idx);
      float wgt = (myE < cnt) ? __expf(lee - m) * inv_z : 0.f;
      uint4 v = ((const uint4*)(hb + (size_t)ss * 256))[l16];
      float f[8]; unpack8(v, f);
#pragma unroll
      for (int i = 0; i < 8; i++) acc[i] = fmaf(wgt, f[i], acc[i]);
    }
  };
  gather(s0, le0, cnt0);
  for (int base = 64; base < deg; base += 64) {
    int cnt = min(64, deg - base);
    int s2 = 0; float le2 = -3e38f;
    if (lane < cnt) { s2 = col_src[lo + base + lane]; le2 = leaky(as_[s2] + adn); }
    gather(s2, le2, cnt);
  }

#pragma unroll
  for (int i = 0; i < 8; i++) acc[i] += __shfl_xor(acc[i], 32);

  if (half == 0) {
    float4 b0 = *(const float4*)&bias[l16 * 8];
    float4 b1 = *(const float4*)&bias[l16 * 8 + 4];
    float o[8] = {acc[0]+b0.x, acc[1]+b0.y, acc[2]+b0.z, acc[3]+b0.w,
                  acc[4]+b1.x, acc[5]+b1.y, acc[6]+b1.z, acc[7]+b1.w};
    if (relu_out) {
#pragma unroll
      for (int i = 0; i < 8; i++) o[i] = fmaxf(o[i], 0.f);
    }
    *(float4*)&out[(size_t)node * 256 + l16 * 8]     = make_float4(o[0],o[1],o[2],o[3]);
    *(float4*)&out[(size_t)node * 256 + l16 * 8 + 4] = make_float4(o[4],o[5],o[6],o[7]);
  }
}

// ---------------- BN stats ----------------
__global__ __launch_bounds__(256) void bn_stats(const float* __restrict__ h, int n,
                                                float* __restrict__ bsum,
                                                float* __restrict__ bsq) {
  int c = threadIdx.x;
  int rows_per_block = (n + gridDim.x - 1) / gridDim.x;
  int r0 = blockIdx.x * rows_per_block;
  int r1 = min(r0 + rows_per_block, n);
  float sum = 0.f, sq = 0.f;
  for (int r = r0; r < r1; r++) {
    float v = h[(size_t)r * 256 + c];
    sum += v;
    sq = fmaf(v, v, sq);
  }
  atomicAdd(&bsum[c], sum);
  atomicAdd(&bsq[c], sq);
}

// ---------------- BN apply + ReLU -> bf16 for GEMM2 ----------------
__global__ __launch_bounds__(256) void bn_apply(const float* __restrict__ h,
                                                const float* __restrict__ bsum,
                                                const float* __restrict__ bsq,
                                                const float* __restrict__ gamma,
                                                const float* __restrict__ beta,
                                                ushort_t* __restrict__ h2b, int n) {
  int total4 = n * 64;
  float inv_n = 1.0f / (float)n;
  for (int f = blockIdx.x * blockDim.x + threadIdx.x; f < total4;
       f += gridDim.x * blockDim.x) {
    int c4 = f & 63;
    float4 v = ((const float4*)h)[f];
    float4 sm = ((const float4*)bsum)[c4];
    float4 sl = ((const float4*)bsq)[c4];
    float4 g = ((const float4*)gamma)[c4];
    float4 bb = ((const float4*)beta)[c4];
    float m, var;
    m = sm.x * inv_n; var = sl.x * inv_n - m * m;
    v.x = fmaxf(g.x * (v.x - m) * rsqrtf(var + 1e-5f) + bb.x, 0.f);
    m = sm.y * inv_n; var = sl.y * inv_n - m * m;
    v.y = fmaxf(g.y * (v.y - m) * rsqrtf(var + 1e-5f) + bb.y, 0.f);
    m = sm.z * inv_n; var = sl.z * inv_n - m * m;
    v.z = fmaxf(g.z * (v.z - m) * rsqrtf(var + 1e-5f) + bb.z, 0.f);
    m = sm.w * inv_n; var = sl.w * inv_n - m * m;
    v.w = fmaxf(g.w * (v.w - m) * rsqrtf(var + 1e-5f) + bb.w, 0.f);
    *(ushort4*)&h2b[(size_t)f * 4] =
        make_ushort4(f2bf(v.x), f2bf(v.y), f2bf(v.z), f2bf(v.w));
  }
}

// ---------------- mean pool: partial sums (graph x chunk grid) ----------------
__device__ inline int lower_bound_dev(const int* a, int n, int v) {
  int lo = 0, hi = n;
  while (lo < hi) {
    int mid = (lo + hi) >> 1;
    if (a[mid] < v) lo = mid + 1; else hi = mid;
  }
  return lo;
}

#define POOL_CHUNKS 16
__global__ __launch_bounds__(256) void pool_partial(const float* __restrict__ h,
                                                    const int* __restrict__ batch, int n,
                                                    float* __restrict__ psum) {
  int g = blockIdx.x / POOL_CHUNKS;
  int c = blockIdx.x % POOL_CHUNKS;
  int lo = lower_bound_dev(batch, n, g);
  int hi = lower_bound_dev(batch, n, g + 1);
  int len = hi - lo;
  int r0 = lo + (int)(((long long)len * c) / POOL_CHUNKS);
  int r1 = lo + (int)(((long long)len * (c + 1)) / POOL_CHUNKS);
  if (r1 <= r0) return;
  float sum = 0.f;
  for (int r = r0; r < r1; r++) sum += h[(size_t)r * 256 + threadIdx.x];
  atomicAdd(&psum[(size_t)g * 256 + threadIdx.x], sum);
}

// ---------------- final head (divides pooled sum by count) ----------------
__global__ __launch_bounds__(256) void final_kernel(const float* __restrict__ psum,
                                                    const int* __restrict__ batch, int n,
                                                    const float* __restrict__ ce,
                                                    const float* __restrict__ Wc,
                                                    const float* __restrict__ bc,
                                                    float* __restrict__ out, int B) {
  int g = blockIdx.x;
  int t = threadIdx.x;
  int lo = lower_bound_dev(batch, n, g);
  int hi = lower_bound_dev(batch, n, g + 1);
  float inv_cnt = 1.0f / fmaxf((float)(hi - lo), 1.0f);
  float p = 0.f;
  p = fmaf(psum[(size_t)g * 256 + t] * inv_cnt, Wc[t], p);
  p = fmaf(ce[(size_t)g * 768 + t],        Wc[256 + t], p);
  p = fmaf(ce[(size_t)g * 768 + 256 + t],  Wc[512 + t], p);
  p = fmaf(ce[(size_t)g * 768 + 512 + t],  Wc[768 + t], p);
  __shared__ float red[256];
  red[t] = p;
  __syncthreads();
  for (int s = 128; s; s >>= 1) {
    if (t < s) red[t] += red[t + s];
    __syncthreads();
  }
  if (t == 0) out[g] = red[0] + bc[0];
}

// ---------------- launch ----------------
extern "C" void kernel_launch(void* const* d_in, const int* in_sizes, int n_in,
                              void* d_out, int out_size, void* d_ws, size_t ws_size,
                              hipStream_t stream) {
  const float* ce    = (const float*)d_in[0];
  const float* x     = (const float*)d_in[1];
  const int*   edge  = (const int*)d_in[2];
  const int*   batch = (const int*)d_in[3];
  const float* W1    = (const float*)d_in[4];
  const float* a_s1  = (const float*)d_in[5];
  const float* a_d1  = (const float*)d_in[6];
  const float* b1    = (const float*)d_in[7];
  const float* W2    = (const float*)d_in[8];
  const float* a_s2  = (const float*)d_in[9];
  const float* a_d2  = (const float*)d_in[10];
  const float* b2    = (const float*)d_in[11];
  const float* gamma = (const float*)d_in[12];
  const float* beta  = (const float*)d_in[13];
  const float* Wc    = (const float*)d_in[14];
  const float* bc    = (const float*)d_in[15];

  const int B = in_sizes[0] / DIN;
  const int n = in_sizes[1] / DIN;
  const int E = in_sizes[2] / 2;
  const int* esrc = edge;
  const int* edst = edge + E;

  char* w = (char*)d_ws;
  size_t off = 0;
  auto carve = [&](size_t bytes) -> void* {
    void* p = w + off;
    off = (off + bytes + 255) & ~(size_t)255;
    return p;
  };
  size_t xb_bytes   = (size_t)n * DIN * 2;
  size_t bufo_bytes = (size_t)n * DH * 4;
  char*  R1       = (char*)carve(xb_bytes);
  ushort_t* xb    = (ushort_t*)R1;
  float*    buf_o = (float*)R1;
  ushort_t* h2b   = (ushort_t*)(R1 + bufo_bytes);
  ushort_t* buf_hb = (ushort_t*)carve((size_t)n * DH * 2);
  int*   cnt     = (int*)carve((size_t)n * 4);
  int*   row_off = (int*)carve((size_t)(n + 1) * 4);
  int*   fill    = (int*)carve((size_t)n * 4);
  int*   col_src = (int*)carve((size_t)E * 4);
  float* alpha_s = (float*)carve((size_t)n * 4);
  float* alpha_d = (float*)carve((size_t)n * 4);
  float* bn_sum  = (float*)carve(DH * 4);
  float* bn_sq   = (float*)carve(DH * 4);
  float* psum    = (float*)carve((size_t)B * DH * 4);
  ushort_t* Wt1  = (ushort_t*)carve((size_t)DIN * DH * 2);
  ushort_t* Wt2  = (ushort_t*)carve((size_t)DH * DH * 2);

  hipMemsetAsync(cnt, 0, (size_t)n * 4, stream);
  hipMemsetAsync(fill, 0, (size_t)n * 4, stream);
  hipMemsetAsync(bn_sum, 0, DH * 4, stream);
  hipMemsetAsync(bn_sq, 0, DH * 4, stream);
  hipMemsetAsync(psum, 0, (size_t)B * DH * 4, stream);

  const int gN4 = (n + 3) / 4;
  const int Mb = (n + 127) / 128;

  wt_kernel<<<(DIN + 255) / 256, 256, 0, stream>>>(W1, Wt1, DIN);
  wt_kernel<<<(DH + 255) / 256, 256, 0, stream>>>(W2, Wt2, DH);
  relxb_kernel<<<gN4, 256, 0, stream>>>(ce, x, batch, xb, n);
  hist_kernel<<<1024, 256, 0, stream>>>(edst, E, cnt);
  scan_kernel<<<1, 1024, 0, stream>>>(cnt, row_off, n);
  fill_kernel<<<1024, 256, 0, stream>>>(esrc, edst, E, row_off, fill, col_src);

  // ---- layer 1 ----
  gemm_mfma<DIN><<<dim3(Mb, 2), 256, 0, stream>>>(xb, Wt1, buf_hb, n);
  alpha_kernel<<<gN4, 256, 0, stream>>>(buf_hb, a_s1, a_d1, alpha_s, alpha_d, n);
  gat_agg<<<gN4, 256, 0, stream>>>(buf_hb, alpha_s, alpha_d, row_off, col_src, b1,
                                   buf_o, n, 0);
  bn_stats<<<512, 256, 0, stream>>>(buf_o, n, bn_sum, bn_sq);
  bn_apply<<<2048, 256, 0, stream>>>(buf_o, bn_sum, bn_sq, gamma, beta, h2b, n);

  // ---- layer 2 ----
  gemm_mfma<DH><<<dim3(Mb, 2), 256, 0, stream>>>(h2b, Wt2, buf_hb, n);
  alpha_kernel<<<gN4, 256, 0, stream>>>(buf_hb, a_s2, a_d2, alpha_s, alpha_d, n);
  gat_agg<<<gN4, 256, 0, stream>>>(buf_hb, alpha_s, alpha_d, row_off, col_src, b2,
                                   buf_o, n, 1);

  // ---- head ----
  pool_partial<<<B * POOL_CHUNKS, 256, 0, stream>>>(buf_o, batch, n, psum);
  final_kernel<<<B, 256, 0, stream>>>(psum, batch, n, ce, Wc, bc, (float*)d_out, B);
}

// Round 5
// 549.747 us; speedup vs baseline: 1.8042x; 1.0183x over previous
//
#include <hip/hip_runtime.h>
#include <hip/hip_bf16.h>

#define DIN 768
#define DH  256

typedef unsigned short ushort_t;
typedef __attribute__((ext_vector_type(8))) short short8v;   // 8 bf16 (4 VGPRs)
typedef __attribute__((ext_vector_type(4))) float f32x4;

__device__ inline float wave_sum(float v) {
#pragma unroll
  for (int o = 32; o; o >>= 1) v += __shfl_xor(v, o);
  return v;
}
__device__ inline float wave_max(float v) {
#pragma unroll
  for (int o = 32; o; o >>= 1) v = fmaxf(v, __shfl_xor(v, o));
  return v;
}
__device__ inline float leaky(float v) { return v > 0.f ? v : 0.2f * v; }

__device__ inline ushort_t f2bf(float f) {
  union { float f; unsigned u; } v; v.f = f;
  unsigned r = v.u + 0x7FFFu + ((v.u >> 16) & 1u);  // RNE
  return (ushort_t)(r >> 16);
}
__device__ inline float bf2f(ushort_t u) {
  union { unsigned u; float f; } t; t.u = ((unsigned)u) << 16; return t.f;
}

__device__ inline void unpack8(uint4 v, float* f) {
  union { unsigned u; float f; } t;
  t.u = v.x << 16;         f[0] = t.f;
  t.u = v.x & 0xFFFF0000u; f[1] = t.f;
  t.u = v.y << 16;         f[2] = t.f;
  t.u = v.y & 0xFFFF0000u; f[3] = t.f;
  t.u = v.z << 16;         f[4] = t.f;
  t.u = v.z & 0xFFFF0000u; f[5] = t.f;
  t.u = v.w << 16;         f[6] = t.f;
  t.u = v.w & 0xFFFF0000u; f[7] = t.f;
}
__device__ inline uint4 pack8(const float* f) {
  uint4 o;
  o.x = (unsigned)f2bf(f[0]) | ((unsigned)f2bf(f[1]) << 16);
  o.y = (unsigned)f2bf(f[2]) | ((unsigned)f2bf(f[3]) << 16);
  o.z = (unsigned)f2bf(f[4]) | ((unsigned)f2bf(f[5]) << 16);
  o.w = (unsigned)f2bf(f[6]) | ((unsigned)f2bf(f[7]) << 16);
  return o;
}

// ---------------- K1: cosine relevance gating + bf16(x*rel) ----------------
__global__ __launch_bounds__(256) void relxb_kernel(
    const float* __restrict__ ce, const float* __restrict__ x,
    const int* __restrict__ batch, ushort_t* __restrict__ xb, int n) {
  int node = blockIdx.x * 4 + (threadIdx.x >> 6);
  int lane = threadIdx.x & 63;
  if (node >= n) return;
  int g = batch[node];
  const float4* xr = (const float4*)(x + (size_t)node * DIN);
  const float4* cr = (const float4*)(ce + (size_t)g * DIN);
  float4 av[3];
  float dxy = 0.f, dxx = 0.f, dcc = 0.f;
#pragma unroll
  for (int i = 0; i < 3; i++) {
    float4 a = xr[lane + 64 * i];
    float4 b = cr[lane + 64 * i];
    av[i] = a;
    dxy += a.x*b.x + a.y*b.y + a.z*b.z + a.w*b.w;
    dxx += a.x*a.x + a.y*a.y + a.z*a.z + a.w*a.w;
    dcc += b.x*b.x + b.y*b.y + b.z*b.z + b.w*b.w;
  }
  dxy = wave_sum(dxy);
  dxx = wave_sum(dxx);
  dcc = wave_sum(dcc);
  float denom = fmaxf(sqrtf(dxx) * sqrtf(dcc), 1e-8f);
  float rel = dxy / denom;
#pragma unroll
  for (int i = 0; i < 3; i++) {
    float4 a = av[i];
    ushort4 o = make_ushort4(f2bf(a.x * rel), f2bf(a.y * rel),
                             f2bf(a.z * rel), f2bf(a.w * rel));
    *(ushort4*)&xb[(size_t)node * DIN + (lane + 64 * i) * 4] = o;
  }
}

// ---------------- W transpose + bf16 cast: W[K][256] -> Wt[256][K] ----------------
__global__ void wt_kernel(const float* __restrict__ W, ushort_t* __restrict__ Wt, int K) {
  int k = blockIdx.x * 256 + threadIdx.x;
  if (k >= K) return;
  for (int c = 0; c < 256; c++)
    Wt[(size_t)c * K + k] = f2bf(W[(size_t)k * 256 + c]);
}

// ---------------- CSR build ----------------
__global__ void hist_kernel(const int* __restrict__ dst, int E, int* __restrict__ cnt) {
  for (int e = blockIdx.x * blockDim.x + threadIdx.x; e < E; e += gridDim.x * blockDim.x)
    atomicAdd(&cnt[dst[e]], 1);
}

__global__ __launch_bounds__(1024) void scan_kernel(const int* __restrict__ cnt,
                                                    int* __restrict__ row_off, int n) {
  __shared__ int s[1024];
  int t = threadIdx.x;
  int chunk = (n + 1023) / 1024;
  int lo = t * chunk, hi = min(lo + chunk, n);
  int sum = 0;
  for (int i = lo; i < hi; i++) sum += cnt[i];
  int mysum = sum;
  s[t] = sum;
  __syncthreads();
  for (int off = 1; off < 1024; off <<= 1) {
    int v = (t >= off) ? s[t - off] : 0;
    __syncthreads();
    s[t] += v;
    __syncthreads();
  }
  int run = s[t] - mysum;
  for (int i = lo; i < hi; i++) { row_off[i] = run; run += cnt[i]; }
  if (t == 1023) row_off[n] = s[1023];
}

__global__ void fill_kernel(const int* __restrict__ src, const int* __restrict__ dst, int E,
                            const int* __restrict__ row_off, int* __restrict__ fill,
                            int* __restrict__ col_src) {
  for (int e = blockIdx.x * blockDim.x + threadIdx.x; e < E; e += gridDim.x * blockDim.x) {
    int d = dst[e];
    int slot = row_off[d] + atomicAdd(&fill[d], 1);
    col_src[slot] = src[e];
  }
}

// ---------------- bf16 MFMA GEMM + fused alpha dots ----------------
// C[M,256](bf16) = A[M,K] @ Bt[256,K]^T; alpha_s/d[row] += C_f32[row,:] . a_s/d
template <int K>
__global__ __launch_bounds__(256) void gemm_mfma(
    const ushort_t* __restrict__ A, const ushort_t* __restrict__ Bt,
    ushort_t* __restrict__ C, const float* __restrict__ a_s,
    const float* __restrict__ a_d, float* __restrict__ alpha_s,
    float* __restrict__ alpha_d, int Mreal) {
  __shared__ ushort_t lds[16384];  // A: [0,8192) shorts, B: [8192,16384)
  const int tid = threadIdx.x;
  const int lane = tid & 63;
  const int wave = tid >> 6;
  const int row0 = blockIdx.x * 128;
  const int col0 = blockIdx.y * 128;
  const int wr = wave >> 1, wc = wave & 1;

  f32x4 acc[4][4];
#pragma unroll
  for (int m = 0; m < 4; m++)
#pragma unroll
    for (int nn = 0; nn < 4; nn++)
#pragma unroll
      for (int j = 0; j < 4; j++) acc[m][nn][j] = 0.f;

  for (int k0 = 0; k0 < K; k0 += 64) {
#pragma unroll
    for (int c = 0; c < 8; c++) {
      int chunk = wave * 8 + c;
      int isB = chunk >> 4;
      int i = chunk & 15;
      int kb = i >> 1, half = i & 1;
      int ldsbase = isB * 8192 + kb * 1024 + half * 512;
      const ushort_t* gsrc;
      int grow = half * 64 + lane;
      if (isB == 0) {
        int r = row0 + grow;
        r = r < Mreal ? r : Mreal - 1;
        gsrc = A + (size_t)r * K + k0 + kb * 8;
      } else {
        gsrc = Bt + (size_t)(col0 + grow) * K + k0 + kb * 8;
      }
      __builtin_amdgcn_global_load_lds(
          (const __attribute__((address_space(1))) void*)gsrc,
          (__attribute__((address_space(3))) void*)&lds[ldsbase], 16, 0, 0);
    }
    __syncthreads();
#pragma unroll
    for (int ks = 0; ks < 2; ks++) {
      short8v a[4], b[4];
#pragma unroll
      for (int m = 0; m < 4; m++) {
        int idx = (ks * 4 + (lane >> 4)) * 1024 + (wr * 64 + m * 16 + (lane & 15)) * 8;
        a[m] = *(const short8v*)&lds[idx];
      }
#pragma unroll
      for (int nn = 0; nn < 4; nn++) {
        int idx = 8192 + (ks * 4 + (lane >> 4)) * 1024 +
                  (wc * 64 + nn * 16 + (lane & 15)) * 8;
        b[nn] = *(const short8v*)&lds[idx];
      }
#pragma unroll
      for (int m = 0; m < 4; m++)
#pragma unroll
        for (int nn = 0; nn < 4; nn++)
          acc[m][nn] = __builtin_amdgcn_mfma_f32_16x16x32_bf16(a[m], b[nn],
                                                               acc[m][nn], 0, 0, 0);
    }
    __syncthreads();
  }

  // preload alpha vectors for my 4 columns
  float asv[4], adv[4];
#pragma unroll
  for (int nn = 0; nn < 4; nn++) {
    int col = col0 + wc * 64 + nn * 16 + (lane & 15);
    asv[nn] = a_s[col];
    adv[nn] = a_d[col];
  }

  // epilogue: store bf16 C + reduce alpha partials
#pragma unroll
  for (int m = 0; m < 4; m++) {
    int row_base = row0 + wr * 64 + m * 16 + (lane >> 4) * 4;
#pragma unroll
    for (int j = 0; j < 4; j++) {
      int row = row_base + j;
      float ps = 0.f, pd = 0.f;
#pragma unroll
      for (int nn = 0; nn < 4; nn++) {
        float v = acc[m][nn][j];
        ps = fmaf(v, asv[nn], ps);
        pd = fmaf(v, adv[nn], pd);
        if (row < Mreal) {
          int col = col0 + wc * 64 + nn * 16 + (lane & 15);
          C[(size_t)row * 256 + col] = f2bf(v);
        }
      }
#pragma unroll
      for (int o = 1; o < 16; o <<= 1) {
        ps += __shfl_xor(ps, o);
        pd += __shfl_xor(pd, o);
      }
      if ((lane & 15) == 0 && row < Mreal) {
        atomicAdd(&alpha_s[row], ps);
        atomicAdd(&alpha_d[row], pd);
      }
    }
  }
}

// ---------------- GAT attention + aggregation (wave per node, bf16 in/out) -------
__global__ __launch_bounds__(256) void gat_agg(
    const ushort_t* __restrict__ hb, const float* __restrict__ as_,
    const float* __restrict__ ad_, const int* __restrict__ row_off,
    const int* __restrict__ col_src, const float* __restrict__ bias,
    ushort_t* __restrict__ outb, int n, int relu_out) {
  int node = blockIdx.x * 4 + (threadIdx.x >> 6);
  int lane = threadIdx.x & 63;
  if (node >= n) return;
  int lo = row_off[node], hi = row_off[node + 1];
  int deg = hi - lo;
  float adn = ad_[node];
  float self_e = leaky(as_[node] + adn);

  int cnt0 = min(deg, 64);
  int s0 = 0; float le0 = -3e38f;
  if (lane < cnt0) { s0 = col_src[lo + lane]; le0 = leaky(as_[s0] + adn); }

  // phase A: max
  float m = fmaxf(self_e, wave_max(le0));
  for (int base = 64; base < deg; base += 64) {
    int cnt = min(64, deg - base);
    float l2 = -3e38f;
    if (lane < cnt) l2 = leaky(as_[col_src[lo + base + lane]] + adn);
    m = fmaxf(m, wave_max(l2));
  }

  // phase B: sum of exp
  float z = wave_sum(lane < cnt0 ? __expf(le0 - m) : 0.f);
  for (int base = 64; base < deg; base += 64) {
    int cnt = min(64, deg - base);
    float ez = 0.f;
    if (lane < cnt) ez = __expf(leaky(as_[col_src[lo + base + lane]] + adn) - m);
    z += wave_sum(ez);
  }
  float ez_self = __expf(self_e - m);
  z += ez_self;
  float inv_z = 1.0f / z;

  // phase C: paired gather (2 edges per half-wave pass, unrolled x2)
  const int half = lane >> 5;
  const int l16 = lane & 31;
  float acc[8];
  {
    uint4 v = ((const uint4*)(hb + (size_t)node * 256))[l16];
    float f[8]; unpack8(v, f);
    float ws = (half == 0) ? ez_self * inv_z : 0.f;
#pragma unroll
    for (int i = 0; i < 8; i++) acc[i] = ws * f[i];
  }

  auto gather = [&](int sreg, float lereg, int cnt) {
    int e = 0;
    for (; e + 4 <= cnt; e += 4) {
      int i1 = e + half, i2 = e + 2 + half;
      int ss1 = __shfl(sreg, i1);
      float le1 = __shfl(lereg, i1);
      int ss2 = __shfl(sreg, i2);
      float le2 = __shfl(lereg, i2);
      uint4 v1 = ((const uint4*)(hb + (size_t)ss1 * 256))[l16];
      uint4 v2 = ((const uint4*)(hb + (size_t)ss2 * 256))[l16];
      float w1 = __expf(le1 - m) * inv_z;
      float w2 = __expf(le2 - m) * inv_z;
      float f1[8]; unpack8(v1, f1);
#pragma unroll
      for (int i = 0; i < 8; i++) acc[i] = fmaf(w1, f1[i], acc[i]);
      float f2[8]; unpack8(v2, f2);
#pragma unroll
      for (int i = 0; i < 8; i++) acc[i] = fmaf(w2, f2[i], acc[i]);
    }
    for (; e < cnt; e += 2) {
      int myE = e + half;
      int idx = myE < cnt ? myE : cnt - 1;
      int ss = __shfl(sreg, idx);
      float lee = __shfl(lereg, idx);
      float wgt = (myE < cnt) ? __expf(lee - m) * inv_z : 0.f;
      uint4 v = ((const uint4*)(hb + (size_t)ss * 256))[l16];
      float f[8]; unpack8(v, f);
#pragma unroll
      for (int i = 0; i < 8; i++) acc[i] = fmaf(wgt, f[i], acc[i]);
    }
  };
  gather(s0, le0, cnt0);
  for (int base = 64; base < deg; base += 64) {
    int cnt = min(64, deg - base);
    int s2 = 0; float le2 = -3e38f;
    if (lane < cnt) { s2 = col_src[lo + base + lane]; le2 = leaky(as_[s2] + adn); }
    gather(s2, le2, cnt);
  }

#pragma unroll
  for (int i = 0; i < 8; i++) acc[i] += __shfl_xor(acc[i], 32);

  if (half == 0) {
    float4 b0 = *(const float4*)&bias[l16 * 8];
    float4 b1 = *(const float4*)&bias[l16 * 8 + 4];
    float o[8] = {acc[0]+b0.x, acc[1]+b0.y, acc[2]+b0.z, acc[3]+b0.w,
                  acc[4]+b1.x, acc[5]+b1.y, acc[6]+b1.z, acc[7]+b1.w};
    if (relu_out) {
#pragma unroll
      for (int i = 0; i < 8; i++) o[i] = fmaxf(o[i], 0.f);
    }
    *(uint4*)&outb[(size_t)node * 256 + l16 * 8] = pack8(o);
  }
}

// ---------------- BN stats (bf16 input) ----------------
__global__ __launch_bounds__(256) void bn_stats(const ushort_t* __restrict__ h, int n,
                                                float* __restrict__ bsum,
                                                float* __restrict__ bsq) {
  int c = threadIdx.x;
  int rows_per_block = (n + gridDim.x - 1) / gridDim.x;
  int r0 = blockIdx.x * rows_per_block;
  int r1 = min(r0 + rows_per_block, n);
  float sum = 0.f, sq = 0.f;
  for (int r = r0; r < r1; r++) {
    float v = bf2f(h[(size_t)r * 256 + c]);
    sum += v;
    sq = fmaf(v, v, sq);
  }
  atomicAdd(&bsum[c], sum);
  atomicAdd(&bsq[c], sq);
}

// ---------------- BN apply + ReLU (bf16 -> bf16) ----------------
__global__ __launch_bounds__(256) void bn_apply(const ushort_t* __restrict__ h,
                                                const float* __restrict__ bsum,
                                                const float* __restrict__ bsq,
                                                const float* __restrict__ gamma,
                                                const float* __restrict__ beta,
                                                ushort_t* __restrict__ h2b, int n) {
  int total4 = n * 64;  // groups of 4 bf16
  float inv_n = 1.0f / (float)n;
  for (int f = blockIdx.x * blockDim.x + threadIdx.x; f < total4;
       f += gridDim.x * blockDim.x) {
    int c4 = f & 63;
    uint2 hv = ((const uint2*)h)[f];
    float v0, v1, v2, v3;
    {
      union { unsigned u; float fl; } t;
      t.u = hv.x << 16;         v0 = t.fl;
      t.u = hv.x & 0xFFFF0000u; v1 = t.fl;
      t.u = hv.y << 16;         v2 = t.fl;
      t.u = hv.y & 0xFFFF0000u; v3 = t.fl;
    }
    float4 sm = ((const float4*)bsum)[c4];
    float4 sl = ((const float4*)bsq)[c4];
    float4 g = ((const float4*)gamma)[c4];
    float4 bb = ((const float4*)beta)[c4];
    float m, var;
    m = sm.x * inv_n; var = sl.x * inv_n - m * m;
    v0 = fmaxf(g.x * (v0 - m) * rsqrtf(var + 1e-5f) + bb.x, 0.f);
    m = sm.y * inv_n; var = sl.y * inv_n - m * m;
    v1 = fmaxf(g.y * (v1 - m) * rsqrtf(var + 1e-5f) + bb.y, 0.f);
    m = sm.z * inv_n; var = sl.z * inv_n - m * m;
    v2 = fmaxf(g.z * (v2 - m) * rsqrtf(var + 1e-5f) + bb.z, 0.f);
    m = sm.w * inv_n; var = sl.w * inv_n - m * m;
    v3 = fmaxf(g.w * (v3 - m) * rsqrtf(var + 1e-5f) + bb.w, 0.f);
    uint2 o;
    o.x = (unsigned)f2bf(v0) | ((unsigned)f2bf(v1) << 16);
    o.y = (unsigned)f2bf(v2) | ((unsigned)f2bf(v3) << 16);
    ((uint2*)h2b)[f] = o;
  }
}

// ---------------- mean pool: partial sums (graph x chunk grid, bf16 in) ----------
__device__ inline int lower_bound_dev(const int* a, int n, int v) {
  int lo = 0, hi = n;
  while (lo < hi) {
    int mid = (lo + hi) >> 1;
    if (a[mid] < v) lo = mid + 1; else hi = mid;
  }
  return lo;
}

#define POOL_CHUNKS 16
__global__ __launch_bounds__(256) void pool_partial(const ushort_t* __restrict__ h,
                                                    const int* __restrict__ batch, int n,
                                                    float* __restrict__ psum) {
  int g = blockIdx.x / POOL_CHUNKS;
  int c = blockIdx.x % POOL_CHUNKS;
  int lo = lower_bound_dev(batch, n, g);
  int hi = lower_bound_dev(batch, n, g + 1);
  int len = hi - lo;
  int r0 = lo + (int)(((long long)len * c) / POOL_CHUNKS);
  int r1 = lo + (int)(((long long)len * (c + 1)) / POOL_CHUNKS);
  if (r1 <= r0) return;
  float sum = 0.f;
  for (int r = r0; r < r1; r++) sum += bf2f(h[(size_t)r * 256 + threadIdx.x]);
  atomicAdd(&psum[(size_t)g * 256 + threadIdx.x], sum);
}

// ---------------- final head ----------------
__global__ __launch_bounds__(256) void final_kernel(const float* __restrict__ psum,
                                                    const int* __restrict__ batch, int n,
                                                    const float* __restrict__ ce,
                                                    const float* __restrict__ Wc,
                                                    const float* __restrict__ bc,
                                                    float* __restrict__ out, int B) {
  int g = blockIdx.x;
  int t = threadIdx.x;
  int lo = lower_bound_dev(batch, n, g);
  int hi = lower_bound_dev(batch, n, g + 1);
  float inv_cnt = 1.0f / fmaxf((float)(hi - lo), 1.0f);
  float p = 0.f;
  p = fmaf(psum[(size_t)g * 256 + t] * inv_cnt, Wc[t], p);
  p = fmaf(ce[(size_t)g * 768 + t],        Wc[256 + t], p);
  p = fmaf(ce[(size_t)g * 768 + 256 + t],  Wc[512 + t], p);
  p = fmaf(ce[(size_t)g * 768 + 512 + t],  Wc[768 + t], p);
  __shared__ float red[256];
  red[t] = p;
  __syncthreads();
  for (int s = 128; s; s >>= 1) {
    if (t < s) red[t] += red[t + s];
    __syncthreads();
  }
  if (t == 0) out[g] = red[0] + bc[0];
}

// ---------------- launch ----------------
extern "C" void kernel_launch(void* const* d_in, const int* in_sizes, int n_in,
                              void* d_out, int out_size, void* d_ws, size_t ws_size,
                              hipStream_t stream) {
  const float* ce    = (const float*)d_in[0];
  const float* x     = (const float*)d_in[1];
  const int*   edge  = (const int*)d_in[2];
  const int*   batch = (const int*)d_in[3];
  const float* W1    = (const float*)d_in[4];
  const float* a_s1  = (const float*)d_in[5];
  const float* a_d1  = (const float*)d_in[6];
  const float* b1    = (const float*)d_in[7];
  const float* W2    = (const float*)d_in[8];
  const float* a_s2  = (const float*)d_in[9];
  const float* a_d2  = (const float*)d_in[10];
  const float* b2    = (const float*)d_in[11];
  const float* gamma = (const float*)d_in[12];
  const float* beta  = (const float*)d_in[13];
  const float* Wc    = (const float*)d_in[14];
  const float* bc    = (const float*)d_in[15];

  const int B = in_sizes[0] / DIN;
  const int n = in_sizes[1] / DIN;
  const int E = in_sizes[2] / 2;
  const int* esrc = edge;
  const int* edst = edge + E;

  char* w = (char*)d_ws;
  size_t off = 0;
  auto carve = [&](size_t bytes) -> void* {
    void* p = w + off;
    off = (off + bytes + 255) & ~(size_t)255;
    return p;
  };
  // R1 (76.8MB): xb lives during GEMM1 only; afterwards reused by
  // h1b (bf16, +0), h2b (bf16, +25.6MB), buf_ob (bf16, +51.2MB).
  size_t hbytes = (size_t)n * DH * 2;            // 25.6 MB
  char*  R1      = (char*)carve((size_t)n * DIN * 2);
  ushort_t* xb    = (ushort_t*)R1;
  ushort_t* h1b   = (ushort_t*)R1;
  ushort_t* h2b   = (ushort_t*)(R1 + hbytes);
  ushort_t* buf_ob = (ushort_t*)(R1 + 2 * hbytes);
  ushort_t* buf_hb = (ushort_t*)carve(hbytes);   // GEMM output (both layers)
  int*   row_off = (int*)carve((size_t)(n + 1) * 4);
  int*   col_src = (int*)carve((size_t)E * 4);
  ushort_t* Wt1  = (ushort_t*)carve((size_t)DIN * DH * 2);
  ushort_t* Wt2  = (ushort_t*)carve((size_t)DH * DH * 2);
  // contiguous zero region (single memset)
  char* zero0 = (char*)carve((size_t)n * 4);     // cnt
  int*   cnt     = (int*)zero0;
  int*   fill    = (int*)carve((size_t)n * 4);
  float* as1buf  = (float*)carve((size_t)n * 4);
  float* ad1buf  = (float*)carve((size_t)n * 4);
  float* as2buf  = (float*)carve((size_t)n * 4);
  float* ad2buf  = (float*)carve((size_t)n * 4);
  float* bn_sum  = (float*)carve(DH * 4);
  float* bn_sq   = (float*)carve(DH * 4);
  float* psum    = (float*)carve((size_t)B * DH * 4);
  size_t zero_bytes = (size_t)((char*)(psum + (size_t)B * DH) - zero0);

  hipMemsetAsync(zero0, 0, zero_bytes, stream);

  const int gN4 = (n + 3) / 4;
  const int Mb = (n + 127) / 128;

  wt_kernel<<<(DIN + 255) / 256, 256, 0, stream>>>(W1, Wt1, DIN);
  wt_kernel<<<(DH + 255) / 256, 256, 0, stream>>>(W2, Wt2, DH);
  relxb_kernel<<<gN4, 256, 0, stream>>>(ce, x, batch, xb, n);
  hist_kernel<<<1024, 256, 0, stream>>>(edst, E, cnt);
  scan_kernel<<<1, 1024, 0, stream>>>(cnt, row_off, n);
  fill_kernel<<<1024, 256, 0, stream>>>(esrc, edst, E, row_off, fill, col_src);

  // ---- layer 1 ----
  gemm_mfma<DIN><<<dim3(Mb, 2), 256, 0, stream>>>(xb, Wt1, buf_hb, a_s1, a_d1,
                                                  as1buf, ad1buf, n);
  gat_agg<<<gN4, 256, 0, stream>>>(buf_hb, as1buf, ad1buf, row_off, col_src, b1,
                                   h1b, n, 0);
  bn_stats<<<512, 256, 0, stream>>>(h1b, n, bn_sum, bn_sq);
  bn_apply<<<2048, 256, 0, stream>>>(h1b, bn_sum, bn_sq, gamma, beta, h2b, n);

  // ---- layer 2 ----
  gemm_mfma<DH><<<dim3(Mb, 2), 256, 0, stream>>>(h2b, Wt2, buf_hb, a_s2, a_d2,
                                                 as2buf, ad2buf, n);
  gat_agg<<<gN4, 256, 0, stream>>>(buf_hb, as2buf, ad2buf, row_off, col_src, b2,
                                   buf_ob, n, 1);

  // ---- head ----
  pool_partial<<<B * POOL_CHUNKS, 256, 0, stream>>>(buf_ob, batch, n, psum);
  final_kernel<<<B, 256, 0, stream>>>(psum, batch, n, ce, Wc, bc, (float*)d_out, B);
}

// Round 6
// 498.903 us; speedup vs baseline: 1.9880x; 1.1019x over previous
//
#include <hip/hip_runtime.h>
#include <hip/hip_bf16.h>

#define DIN 768
#define DH  256

typedef unsigned short ushort_t;
typedef __attribute__((ext_vector_type(8))) short short8v;   // 8 bf16 (4 VGPRs)
typedef __attribute__((ext_vector_type(4))) float f32x4;

// stored-col s -> original-col (within each 64-col block):
//   o = (s & 0x20) | ((s & 1) << 4) | ((s >> 1) & 0xF), plus block base (s & ~63)
__host__ __device__ inline int orig_col(int s) {
  return (s & ~63) | (s & 0x20) | ((s & 1) << 4) | ((s >> 1) & 0xF);
}

__device__ inline float wave_sum(float v) {
#pragma unroll
  for (int o = 32; o; o >>= 1) v += __shfl_xor(v, o);
  return v;
}
__device__ inline float wave_max(float v) {
#pragma unroll
  for (int o = 32; o; o >>= 1) v = fmaxf(v, __shfl_xor(v, o));
  return v;
}
__device__ inline float leaky(float v) { return v > 0.f ? v : 0.2f * v; }

__device__ inline ushort_t f2bf(float f) {
  union { float f; unsigned u; } v; v.f = f;
  unsigned r = v.u + 0x7FFFu + ((v.u >> 16) & 1u);  // RNE
  return (ushort_t)(r >> 16);
}
__device__ inline float bf2f(ushort_t u) {
  union { unsigned u; float f; } t; t.u = ((unsigned)u) << 16; return t.f;
}

__device__ inline void unpack8(uint4 v, float* f) {
  union { unsigned u; float f; } t;
  t.u = v.x << 16;         f[0] = t.f;
  t.u = v.x & 0xFFFF0000u; f[1] = t.f;
  t.u = v.y << 16;         f[2] = t.f;
  t.u = v.y & 0xFFFF0000u; f[3] = t.f;
  t.u = v.z << 16;         f[4] = t.f;
  t.u = v.z & 0xFFFF0000u; f[5] = t.f;
  t.u = v.w << 16;         f[6] = t.f;
  t.u = v.w & 0xFFFF0000u; f[7] = t.f;
}
__device__ inline uint4 pack8(const float* f) {
  uint4 o;
  o.x = (unsigned)f2bf(f[0]) | ((unsigned)f2bf(f[1]) << 16);
  o.y = (unsigned)f2bf(f[2]) | ((unsigned)f2bf(f[3]) << 16);
  o.z = (unsigned)f2bf(f[4]) | ((unsigned)f2bf(f[5]) << 16);
  o.w = (unsigned)f2bf(f[6]) | ((unsigned)f2bf(f[7]) << 16);
  return o;
}

// ---------------- K1: cosine relevance gating + bf16(x*rel) ----------------
__global__ __launch_bounds__(256) void relxb_kernel(
    const float* __restrict__ ce, const float* __restrict__ x,
    const int* __restrict__ batch, ushort_t* __restrict__ xb, int n) {
  int node = blockIdx.x * 4 + (threadIdx.x >> 6);
  int lane = threadIdx.x & 63;
  if (node >= n) return;
  int g = batch[node];
  const float4* xr = (const float4*)(x + (size_t)node * DIN);
  const float4* cr = (const float4*)(ce + (size_t)g * DIN);
  float4 av[3];
  float dxy = 0.f, dxx = 0.f, dcc = 0.f;
#pragma unroll
  for (int i = 0; i < 3; i++) {
    float4 a = xr[lane + 64 * i];
    float4 b = cr[lane + 64 * i];
    av[i] = a;
    dxy += a.x*b.x + a.y*b.y + a.z*b.z + a.w*b.w;
    dxx += a.x*a.x + a.y*a.y + a.z*a.z + a.w*a.w;
    dcc += b.x*b.x + b.y*b.y + b.z*b.z + b.w*b.w;
  }
  dxy = wave_sum(dxy);
  dxx = wave_sum(dxx);
  dcc = wave_sum(dcc);
  float denom = fmaxf(sqrtf(dxx) * sqrtf(dcc), 1e-8f);
  float rel = dxy / denom;
#pragma unroll
  for (int i = 0; i < 3; i++) {
    float4 a = av[i];
    ushort4 o = make_ushort4(f2bf(a.x * rel), f2bf(a.y * rel),
                             f2bf(a.z * rel), f2bf(a.w * rel));
    *(ushort4*)&xb[(size_t)node * DIN + (lane + 64 * i) * 4] = o;
  }
}

// ---------------- W transpose + bf16 cast: W[K][256] -> Wt[256][K] ----------------
// permK=1: permute the k axis (for GEMM2, whose A rows are stored-permuted).
__global__ void wt_kernel(const float* __restrict__ W, ushort_t* __restrict__ Wt,
                          int K, int permK) {
  int k = blockIdx.x * 256 + threadIdx.x;
  if (k >= K) return;
  int ko = permK ? orig_col(k) : k;
  for (int c = 0; c < 256; c++)
    Wt[(size_t)c * K + k] = f2bf(W[(size_t)ko * 256 + c]);
}

// ---------------- permute per-column vectors into stored space ----------------
__global__ void perm_kernel(const float* __restrict__ b1, const float* __restrict__ b2,
                            const float* __restrict__ gamma, const float* __restrict__ beta,
                            const float* __restrict__ Wc,
                            float* __restrict__ pb1, float* __restrict__ pb2,
                            float* __restrict__ pgamma, float* __restrict__ pbeta,
                            float* __restrict__ pWc) {
  int t = threadIdx.x;          // 0..255
  int o = orig_col(t);
  pb1[t] = b1[o];
  pb2[t] = b2[o];
  pgamma[t] = gamma[o];
  pbeta[t] = beta[o];
  pWc[t] = Wc[o];
}

// ---------------- CSR build ----------------
__global__ void hist_kernel(const int* __restrict__ dst, int E, int* __restrict__ cnt) {
  for (int e = blockIdx.x * blockDim.x + threadIdx.x; e < E; e += gridDim.x * blockDim.x)
    atomicAdd(&cnt[dst[e]], 1);
}

__global__ __launch_bounds__(1024) void scan_kernel(const int* __restrict__ cnt,
                                                    int* __restrict__ row_off, int n) {
  __shared__ int s[1024];
  int t = threadIdx.x;
  int chunk = (n + 1023) / 1024;
  int lo = t * chunk, hi = min(lo + chunk, n);
  int sum = 0;
  for (int i = lo; i < hi; i++) sum += cnt[i];
  int mysum = sum;
  s[t] = sum;
  __syncthreads();
  for (int off = 1; off < 1024; off <<= 1) {
    int v = (t >= off) ? s[t - off] : 0;
    __syncthreads();
    s[t] += v;
    __syncthreads();
  }
  int run = s[t] - mysum;
  for (int i = lo; i < hi; i++) { row_off[i] = run; run += cnt[i]; }
  if (t == 1023) row_off[n] = s[1023];
}

__global__ void fill_kernel(const int* __restrict__ src, const int* __restrict__ dst, int E,
                            const int* __restrict__ row_off, int* __restrict__ fill,
                            int* __restrict__ col_src) {
  for (int e = blockIdx.x * blockDim.x + threadIdx.x; e < E; e += gridDim.x * blockDim.x) {
    int d = dst[e];
    int slot = row_off[d] + atomicAdd(&fill[d], 1);
    col_src[slot] = src[e];
  }
}

// ---------------- bf16 MFMA GEMM + fused alpha dots (coalesced staging/stores) ----
// C stored with per-64-block col permutation (see orig_col). LDS row-major
// [row][64k] with XOR chunk swizzle applied on the GLOBAL SOURCE (linear LDS
// dest, global_load_lds) and on the ds_read side — both-sides involution.
template <int K>
__global__ __launch_bounds__(256) void gemm_mfma(
    const ushort_t* __restrict__ A, const ushort_t* __restrict__ Bt,
    ushort_t* __restrict__ C, const float* __restrict__ a_s,
    const float* __restrict__ a_d, float* __restrict__ alpha_s,
    float* __restrict__ alpha_d, int Mreal) {
  __shared__ ushort_t lds[16384];  // A rows [0,8192) shorts, B rows [8192,16384)
  const int tid = threadIdx.x;
  const int lane = tid & 63;
  const int wave = tid >> 6;
  const int col0 = blockIdx.x * 128;   // x fastest: both col-halves share A rows
  const int row0 = blockIdx.y * 128;
  const int wr = wave >> 1, wc = wave & 1;
  const int c16 = lane & 15, g4 = lane >> 4;

  // staging lane constants: 8 lanes cover one row's 128B; chunk pre-swizzled
  const int st_roff = lane >> 3;            // row within 8-row group
  const int st_gsrc = (lane & 7) ^ st_roff; // global k-chunk for this lane

  f32x4 acc[4][4];
#pragma unroll
  for (int m = 0; m < 4; m++)
#pragma unroll
    for (int nn = 0; nn < 4; nn++)
#pragma unroll
      for (int j = 0; j < 4; j++) acc[m][nn][j] = 0.f;

  for (int k0 = 0; k0 < K; k0 += 64) {
#pragma unroll
    for (int ci = 0; ci < 8; ci++) {
      int inst = wave * 8 + ci;   // 0..31
      int isB = inst >> 4;
      int idx = inst & 15;        // 8-row group within operand
      int lrow = idx * 8 + st_roff;
      const ushort_t* gsrc;
      if (isB == 0) {
        int rg = row0 + lrow;
        rg = rg < Mreal ? rg : Mreal - 1;
        gsrc = A + (size_t)rg * K + k0 + st_gsrc * 8;
      } else {
        gsrc = Bt + (size_t)(col0 + lrow) * K + k0 + st_gsrc * 8;
      }
      __builtin_amdgcn_global_load_lds(
          (const __attribute__((address_space(1))) void*)gsrc,
          (__attribute__((address_space(3))) void*)&lds[isB * 8192 + idx * 512],
          16, 0, 0);
    }
    __syncthreads();
#pragma unroll
    for (int ks = 0; ks < 2; ks++) {
      int g = ks * 4 + g4;
      short8v a[4], b[4];
#pragma unroll
      for (int m = 0; m < 4; m++) {
        int ra = wr * 64 + m * 16 + c16;
        a[m] = *(const short8v*)&lds[ra * 64 + (g ^ (ra & 7)) * 8];
      }
#pragma unroll
      for (int nn = 0; nn < 4; nn++) {
        int rb = wc * 64 + nn * 16 + c16;
        b[nn] = *(const short8v*)&lds[8192 + rb * 64 + (g ^ (rb & 7)) * 8];
      }
#pragma unroll
      for (int m = 0; m < 4; m++)
#pragma unroll
        for (int nn = 0; nn < 4; nn++)
          acc[m][nn] = __builtin_amdgcn_mfma_f32_16x16x32_bf16(a[m], b[nn],
                                                               acc[m][nn], 0, 0, 0);
    }
    __syncthreads();
  }

  // alpha vectors for my 4 ORIGINAL columns (dot is permutation-invariant)
  float asv[4], adv[4];
#pragma unroll
  for (int nn = 0; nn < 4; nn++) {
    int col = col0 + wc * 64 + nn * 16 + c16;
    asv[nn] = a_s[col];
    adv[nn] = a_d[col];
  }

  uint* Cw = (uint*)C;
#pragma unroll
  for (int m = 0; m < 4; m++) {
    int row_base = row0 + wr * 64 + m * 16 + g4 * 4;
#pragma unroll
    for (int j = 0; j < 4; j++) {
      int row = row_base + j;
      float ps = 0.f, pd = 0.f;
#pragma unroll
      for (int nn = 0; nn < 4; nn++) {
        float v = acc[m][nn][j];
        ps = fmaf(v, asv[nn], ps);
        pd = fmaf(v, adv[nn], pd);
      }
#pragma unroll
      for (int o = 1; o < 16; o <<= 1) {
        ps += __shfl_xor(ps, o);
        pd += __shfl_xor(pd, o);
      }
      if (c16 == 0 && row < Mreal) {
        atomicAdd(&alpha_s[row], ps);
        atomicAdd(&alpha_d[row], pd);
      }
      if (row < Mreal) {
#pragma unroll
        for (int q = 0; q < 2; q++) {
          unsigned wv = (unsigned)f2bf(acc[m][2 * q][j]) |
                        ((unsigned)f2bf(acc[m][2 * q + 1][j]) << 16);
          Cw[(size_t)row * 128 + (col0 >> 1) + wc * 32 + q * 16 + c16] = wv;
        }
      }
    }
  }
}

// ---------------- GAT attention + aggregation (wave per node, bf16 in/out) -------
__global__ __launch_bounds__(256) void gat_agg(
    const ushort_t* __restrict__ hb, const float* __restrict__ as_,
    const float* __restrict__ ad_, const int* __restrict__ row_off,
    const int* __restrict__ col_src, const float* __restrict__ bias,
    ushort_t* __restrict__ outb, int n, int relu_out) {
  int node = blockIdx.x * 4 + (threadIdx.x >> 6);
  int lane = threadIdx.x & 63;
  if (node >= n) return;
  int lo = row_off[node], hi = row_off[node + 1];
  int deg = hi - lo;
  float adn = ad_[node];
  float self_e = leaky(as_[node] + adn);

  int cnt0 = min(deg, 64);
  int s0 = 0; float le0 = -3e38f;
  if (lane < cnt0) { s0 = col_src[lo + lane]; le0 = leaky(as_[s0] + adn); }

  float m = fmaxf(self_e, wave_max(le0));
  for (int base = 64; base < deg; base += 64) {
    int cnt = min(64, deg - base);
    float l2 = -3e38f;
    if (lane < cnt) l2 = leaky(as_[col_src[lo + base + lane]] + adn);
    m = fmaxf(m, wave_max(l2));
  }

  float z = wave_sum(lane < cnt0 ? __expf(le0 - m) : 0.f);
  for (int base = 64; base < deg; base += 64) {
    int cnt = min(64, deg - base);
    float ez = 0.f;
    if (lane < cnt) ez = __expf(leaky(as_[col_src[lo + base + lane]] + adn) - m);
    z += wave_sum(ez);
  }
  float ez_self = __expf(self_e - m);
  z += ez_self;
  float inv_z = 1.0f / z;

  const int half = lane >> 5;
  const int l16 = lane & 31;
  float acc[8];
  {
    uint4 v = ((const uint4*)(hb + (size_t)node * 256))[l16];
    float f[8]; unpack8(v, f);
    float ws = (half == 0) ? ez_self * inv_z : 0.f;
#pragma unroll
    for (int i = 0; i < 8; i++) acc[i] = ws * f[i];
  }

  auto gather = [&](int sreg, float lereg, int cnt) {
    int e = 0;
    for (; e + 4 <= cnt; e += 4) {
      int i1 = e + half, i2 = e + 2 + half;
      int ss1 = __shfl(sreg, i1);
      float le1 = __shfl(lereg, i1);
      int ss2 = __shfl(sreg, i2);
      float le2 = __shfl(lereg, i2);
      uint4 v1 = ((const uint4*)(hb + (size_t)ss1 * 256))[l16];
      uint4 v2 = ((const uint4*)(hb + (size_t)ss2 * 256))[l16];
      float w1 = __expf(le1 - m) * inv_z;
      float w2 = __expf(le2 - m) * inv_z;
      float f1[8]; unpack8(v1, f1);
#pragma unroll
      for (int i = 0; i < 8; i++) acc[i] = fmaf(w1, f1[i], acc[i]);
      float f2[8]; unpack8(v2, f2);
#pragma unroll
      for (int i = 0; i < 8; i++) acc[i] = fmaf(w2, f2[i], acc[i]);
    }
    for (; e < cnt; e += 2) {
      int myE = e + half;
      int idx = myE < cnt ? myE : cnt - 1;
      int ss = __shfl(sreg, idx);
      float lee = __shfl(lereg, idx);
      float wgt = (myE < cnt) ? __expf(lee - m) * inv_z : 0.f;
      uint4 v = ((const uint4*)(hb + (size_t)ss * 256))[l16];
      float f[8]; unpack8(v, f);
#pragma unroll
      for (int i = 0; i < 8; i++) acc[i] = fmaf(wgt, f[i], acc[i]);
    }
  };
  gather(s0, le0, cnt0);
  for (int base = 64; base < deg; base += 64) {
    int cnt = min(64, deg - base);
    int s2 = 0; float le2 = -3e38f;
    if (lane < cnt) { s2 = col_src[lo + base + lane]; le2 = leaky(as_[s2] + adn); }
    gather(s2, le2, cnt);
  }

#pragma unroll
  for (int i = 0; i < 8; i++) acc[i] += __shfl_xor(acc[i], 32);

  if (half == 0) {
    float4 b0 = *(const float4*)&bias[l16 * 8];
    float4 b1 = *(const float4*)&bias[l16 * 8 + 4];
    float o[8] = {acc[0]+b0.x, acc[1]+b0.y, acc[2]+b0.z, acc[3]+b0.w,
                  acc[4]+b1.x, acc[5]+b1.y, acc[6]+b1.z, acc[7]+b1.w};
    if (relu_out) {
#pragma unroll
      for (int i = 0; i < 8; i++) o[i] = fmaxf(o[i], 0.f);
    }
    *(uint4*)&outb[(size_t)node * 256 + l16 * 8] = pack8(o);
  }
}

// ---------------- BN stats (bf16 input, stored space) ----------------
__global__ __launch_bounds__(256) void bn_stats(const ushort_t* __restrict__ h, int n,
                                                float* __restrict__ bsum,
                                                float* __restrict__ bsq) {
  int c = threadIdx.x;
  int rows_per_block = (n + gridDim.x - 1) / gridDim.x;
  int r0 = blockIdx.x * rows_per_block;
  int r1 = min(r0 + rows_per_block, n);
  float sum = 0.f, sq = 0.f;
  for (int r = r0; r < r1; r++) {
    float v = bf2f(h[(size_t)r * 256 + c]);
    sum += v;
    sq = fmaf(v, v, sq);
  }
  atomicAdd(&bsum[c], sum);
  atomicAdd(&bsq[c], sq);
}

// ---------------- BN apply + ReLU (bf16 -> bf16, stored space) ----------------
__global__ __launch_bounds__(256) void bn_apply(const ushort_t* __restrict__ h,
                                                const float* __restrict__ bsum,
                                                const float* __restrict__ bsq,
                                                const float* __restrict__ gamma,
                                                const float* __restrict__ beta,
                                                ushort_t* __restrict__ h2b, int n) {
  int total4 = n * 64;  // groups of 4 bf16
  float inv_n = 1.0f / (float)n;
  for (int f = blockIdx.x * blockDim.x + threadIdx.x; f < total4;
       f += gridDim.x * blockDim.x) {
    int c4 = f & 63;
    uint2 hv = ((const uint2*)h)[f];
    float v0, v1, v2, v3;
    {
      union { unsigned u; float fl; } t;
      t.u = hv.x << 16;         v0 = t.fl;
      t.u = hv.x & 0xFFFF0000u; v1 = t.fl;
      t.u = hv.y << 16;         v2 = t.fl;
      t.u = hv.y & 0xFFFF0000u; v3 = t.fl;
    }
    float4 sm = ((const float4*)bsum)[c4];
    float4 sl = ((const float4*)bsq)[c4];
    float4 g = ((const float4*)gamma)[c4];
    float4 bb = ((const float4*)beta)[c4];
    float m, var;
    m = sm.x * inv_n; var = sl.x * inv_n - m * m;
    v0 = fmaxf(g.x * (v0 - m) * rsqrtf(var + 1e-5f) + bb.x, 0.f);
    m = sm.y * inv_n; var = sl.y * inv_n - m * m;
    v1 = fmaxf(g.y * (v1 - m) * rsqrtf(var + 1e-5f) + bb.y, 0.f);
    m = sm.z * inv_n; var = sl.z * inv_n - m * m;
    v2 = fmaxf(g.z * (v2 - m) * rsqrtf(var + 1e-5f) + bb.z, 0.f);
    m = sm.w * inv_n; var = sl.w * inv_n - m * m;
    v3 = fmaxf(g.w * (v3 - m) * rsqrtf(var + 1e-5f) + bb.w, 0.f);
    uint2 o;
    o.x = (unsigned)f2bf(v0) | ((unsigned)f2bf(v1) << 16);
    o.y = (unsigned)f2bf(v2) | ((unsigned)f2bf(v3) << 16);
    ((uint2*)h2b)[f] = o;
  }
}

// ---------------- mean pool: partial sums (graph x chunk grid, bf16 in) ----------
__device__ inline int lower_bound_dev(const int* a, int n, int v) {
  int lo = 0, hi = n;
  while (lo < hi) {
    int mid = (lo + hi) >> 1;
    if (a[mid] < v) lo = mid + 1; else hi = mid;
  }
  return lo;
}

#define POOL_CHUNKS 16
__global__ __launch_bounds__(256) void pool_partial(const ushort_t* __restrict__ h,
                                                    const int* __restrict__ batch, int n,
                                                    float* __restrict__ psum) {
  int g = blockIdx.x / POOL_CHUNKS;
  int c = blockIdx.x % POOL_CHUNKS;
  int lo = lower_bound_dev(batch, n, g);
  int hi = lower_bound_dev(batch, n, g + 1);
  int len = hi - lo;
  int r0 = lo + (int)(((long long)len * c) / POOL_CHUNKS);
  int r1 = lo + (int)(((long long)len * (c + 1)) / POOL_CHUNKS);
  if (r1 <= r0) return;
  float sum = 0.f;
  for (int r = r0; r < r1; r++) sum += bf2f(h[(size_t)r * 256 + threadIdx.x]);
  atomicAdd(&psum[(size_t)g * 256 + threadIdx.x], sum);
}

// ---------------- final head (pooled part uses permuted Wc) ----------------
__global__ __launch_bounds__(256) void final_kernel(const float* __restrict__ psum,
                                                    const int* __restrict__ batch, int n,
                                                    const float* __restrict__ ce,
                                                    const float* __restrict__ pWc,
                                                    const float* __restrict__ Wc,
                                                    const float* __restrict__ bc,
                                                    float* __restrict__ out, int B) {
  int g = blockIdx.x;
  int t = threadIdx.x;
  int lo = lower_bound_dev(batch, n, g);
  int hi = lower_bound_dev(batch, n, g + 1);
  float inv_cnt = 1.0f / fmaxf((float)(hi - lo), 1.0f);
  float p = 0.f;
  p = fmaf(psum[(size_t)g * 256 + t] * inv_cnt, pWc[t], p);
  p = fmaf(ce[(size_t)g * 768 + t],        Wc[256 + t], p);
  p = fmaf(ce[(size_t)g * 768 + 256 + t],  Wc[512 + t], p);
  p = fmaf(ce[(size_t)g * 768 + 512 + t],  Wc[768 + t], p);
  __shared__ float red[256];
  red[t] = p;
  __syncthreads();
  for (int s = 128; s; s >>= 1) {
    if (t < s) red[t] += red[t + s];
    __syncthreads();
  }
  if (t == 0) out[g] = red[0] + bc[0];
}

// ---------------- launch ----------------
extern "C" void kernel_launch(void* const* d_in, const int* in_sizes, int n_in,
                              void* d_out, int out_size, void* d_ws, size_t ws_size,
                              hipStream_t stream) {
  const float* ce    = (const float*)d_in[0];
  const float* x     = (const float*)d_in[1];
  const int*   edge  = (const int*)d_in[2];
  const int*   batch = (const int*)d_in[3];
  const float* W1    = (const float*)d_in[4];
  const float* a_s1  = (const float*)d_in[5];
  const float* a_d1  = (const float*)d_in[6];
  const float* b1    = (const float*)d_in[7];
  const float* W2    = (const float*)d_in[8];
  const float* a_s2  = (const float*)d_in[9];
  const float* a_d2  = (const float*)d_in[10];
  const float* b2    = (const float*)d_in[11];
  const float* gamma = (const float*)d_in[12];
  const float* beta  = (const float*)d_in[13];
  const float* Wc    = (const float*)d_in[14];
  const float* bc    = (const float*)d_in[15];

  const int B = in_sizes[0] / DIN;
  const int n = in_sizes[1] / DIN;
  const int E = in_sizes[2] / 2;
  const int* esrc = edge;
  const int* edst = edge + E;

  char* w = (char*)d_ws;
  size_t off = 0;
  auto carve = [&](size_t bytes) -> void* {
    void* p = w + off;
    off = (off + bytes + 255) & ~(size_t)255;
    return p;
  };
  // R1 (76.8MB): xb lives during GEMM1 only; afterwards reused by
  // h1b (bf16, +0), h2b (bf16, +25.6MB), buf_ob (bf16, +51.2MB).
  size_t hbytes = (size_t)n * DH * 2;            // 25.6 MB
  char*  R1      = (char*)carve((size_t)n * DIN * 2);
  ushort_t* xb    = (ushort_t*)R1;
  ushort_t* h1b   = (ushort_t*)R1;
  ushort_t* h2b   = (ushort_t*)(R1 + hbytes);
  ushort_t* buf_ob = (ushort_t*)(R1 + 2 * hbytes);
  ushort_t* buf_hb = (ushort_t*)carve(hbytes);   // GEMM output (both layers)
  int*   row_off = (int*)carve((size_t)(n + 1) * 4);
  int*   col_src = (int*)carve((size_t)E * 4);
  ushort_t* Wt1  = (ushort_t*)carve((size_t)DIN * DH * 2);
  ushort_t* Wt2  = (ushort_t*)carve((size_t)DH * DH * 2);
  float* pb1     = (float*)carve(DH * 4);
  float* pb2     = (float*)carve(DH * 4);
  float* pgamma  = (float*)carve(DH * 4);
  float* pbeta   = (float*)carve(DH * 4);
  float* pWc     = (float*)carve(DH * 4);
  // contiguous zero region (single memset)
  char* zero0 = (char*)carve((size_t)n * 4);     // cnt
  int*   cnt     = (int*)zero0;
  int*   fill    = (int*)carve((size_t)n * 4);
  float* as1buf  = (float*)carve((size_t)n * 4);
  float* ad1buf  = (float*)carve((size_t)n * 4);
  float* as2buf  = (float*)carve((size_t)n * 4);
  float* ad2buf  = (float*)carve((size_t)n * 4);
  float* bn_sum  = (float*)carve(DH * 4);
  float* bn_sq   = (float*)carve(DH * 4);
  float* psum    = (float*)carve((size_t)B * DH * 4);
  size_t zero_bytes = (size_t)((char*)(psum + (size_t)B * DH) - zero0);

  hipMemsetAsync(zero0, 0, zero_bytes, stream);

  const int gN4 = (n + 3) / 4;
  const int Mb = (n + 127) / 128;

  wt_kernel<<<(DIN + 255) / 256, 256, 0, stream>>>(W1, Wt1, DIN, 0);
  wt_kernel<<<(DH + 255) / 256, 256, 0, stream>>>(W2, Wt2, DH, 1);
  perm_kernel<<<1, 256, 0, stream>>>(b1, b2, gamma, beta, Wc,
                                     pb1, pb2, pgamma, pbeta, pWc);
  relxb_kernel<<<gN4, 256, 0, stream>>>(ce, x, batch, xb, n);
  hist_kernel<<<1024, 256, 0, stream>>>(edst, E, cnt);
  scan_kernel<<<1, 1024, 0, stream>>>(cnt, row_off, n);
  fill_kernel<<<1024, 256, 0, stream>>>(esrc, edst, E, row_off, fill, col_src);

  // ---- layer 1 ----
  gemm_mfma<DIN><<<dim3(2, Mb), 256, 0, stream>>>(xb, Wt1, buf_hb, a_s1, a_d1,
                                                  as1buf, ad1buf, n);
  gat_agg<<<gN4, 256, 0, stream>>>(buf_hb, as1buf, ad1buf, row_off, col_src, pb1,
                                   h1b, n, 0);
  bn_stats<<<512, 256, 0, stream>>>(h1b, n, bn_sum, bn_sq);
  bn_apply<<<2048, 256, 0, stream>>>(h1b, bn_sum, bn_sq, pgamma, pbeta, h2b, n);

  // ---- layer 2 ----
  gemm_mfma<DH><<<dim3(2, Mb), 256, 0, stream>>>(h2b, Wt2, buf_hb, a_s2, a_d2,
                                                 as2buf, ad2buf, n);
  gat_agg<<<gN4, 256, 0, stream>>>(buf_hb, as2buf, ad2buf, row_off, col_src, pb2,
                                   buf_ob, n, 1);

  // ---- head ----
  pool_partial<<<B * POOL_CHUNKS, 256, 0, stream>>>(buf_ob, batch, n, psum);
  final_kernel<<<B, 256, 0, stream>>>(psum, batch, n, ce, pWc, Wc, bc,
                                      (float*)d_out, B);
}

// Round 7
// 479.759 us; speedup vs baseline: 2.0674x; 1.0399x over previous
//
#include <hip/hip_runtime.h>
#include <hip/hip_bf16.h>

#define DIN 768
#define DH  256

typedef unsigned short ushort_t;
typedef __attribute__((ext_vector_type(8))) short short8v;   // 8 bf16 (4 VGPRs)
typedef __attribute__((ext_vector_type(4))) float f32x4;

// stored-col s -> original-col (within each 64-col block):
__host__ __device__ inline int orig_col(int s) {
  return (s & ~63) | (s & 0x20) | ((s & 1) << 4) | ((s >> 1) & 0xF);
}

__device__ inline float wave_sum(float v) {
#pragma unroll
  for (int o = 32; o; o >>= 1) v += __shfl_xor(v, o);
  return v;
}
__device__ inline float wave_max(float v) {
#pragma unroll
  for (int o = 32; o; o >>= 1) v = fmaxf(v, __shfl_xor(v, o));
  return v;
}
__device__ inline float leaky(float v) { return v > 0.f ? v : 0.2f * v; }

__device__ inline ushort_t f2bf(float f) {
  union { float f; unsigned u; } v; v.f = f;
  unsigned r = v.u + 0x7FFFu + ((v.u >> 16) & 1u);  // RNE
  return (ushort_t)(r >> 16);
}
__device__ inline float bf2f(ushort_t u) {
  union { unsigned u; float f; } t; t.u = ((unsigned)u) << 16; return t.f;
}

__device__ inline void unpack8(uint4 v, float* f) {
  union { unsigned u; float f; } t;
  t.u = v.x << 16;         f[0] = t.f;
  t.u = v.x & 0xFFFF0000u; f[1] = t.f;
  t.u = v.y << 16;         f[2] = t.f;
  t.u = v.y & 0xFFFF0000u; f[3] = t.f;
  t.u = v.z << 16;         f[4] = t.f;
  t.u = v.z & 0xFFFF0000u; f[5] = t.f;
  t.u = v.w << 16;         f[6] = t.f;
  t.u = v.w & 0xFFFF0000u; f[7] = t.f;
}
__device__ inline uint4 pack8(const float* f) {
  uint4 o;
  o.x = (unsigned)f2bf(f[0]) | ((unsigned)f2bf(f[1]) << 16);
  o.y = (unsigned)f2bf(f[2]) | ((unsigned)f2bf(f[3]) << 16);
  o.z = (unsigned)f2bf(f[4]) | ((unsigned)f2bf(f[5]) << 16);
  o.w = (unsigned)f2bf(f[6]) | ((unsigned)f2bf(f[7]) << 16);
  return o;
}

// ---------------- K1: cosine relevance gating + bf16(x*rel) ----------------
__global__ __launch_bounds__(256) void relxb_kernel(
    const float* __restrict__ ce, const float* __restrict__ x,
    const int* __restrict__ batch, ushort_t* __restrict__ xb, int n) {
  int node = blockIdx.x * 4 + (threadIdx.x >> 6);
  int lane = threadIdx.x & 63;
  if (node >= n) return;
  int g = batch[node];
  const float4* xr = (const float4*)(x + (size_t)node * DIN);
  const float4* cr = (const float4*)(ce + (size_t)g * DIN);
  float4 av[3];
  float dxy = 0.f, dxx = 0.f, dcc = 0.f;
#pragma unroll
  for (int i = 0; i < 3; i++) {
    float4 a = xr[lane + 64 * i];
    float4 b = cr[lane + 64 * i];
    av[i] = a;
    dxy += a.x*b.x + a.y*b.y + a.z*b.z + a.w*b.w;
    dxx += a.x*a.x + a.y*a.y + a.z*a.z + a.w*a.w;
    dcc += b.x*b.x + b.y*b.y + b.z*b.z + b.w*b.w;
  }
  dxy = wave_sum(dxy);
  dxx = wave_sum(dxx);
  dcc = wave_sum(dcc);
  float denom = fmaxf(sqrtf(dxx) * sqrtf(dcc), 1e-8f);
  float rel = dxy / denom;
#pragma unroll
  for (int i = 0; i < 3; i++) {
    float4 a = av[i];
    ushort4 o = make_ushort4(f2bf(a.x * rel), f2bf(a.y * rel),
                             f2bf(a.z * rel), f2bf(a.w * rel));
    *(ushort4*)&xb[(size_t)node * DIN + (lane + 64 * i) * 4] = o;
  }
}

// ---------------- fused prep: Wt1, Wt2 (permK), permuted per-col vectors ----------
__global__ __launch_bounds__(256) void prep_kernel(
    const float* __restrict__ W1, const float* __restrict__ W2,
    const float* __restrict__ b1, const float* __restrict__ b2,
    const float* __restrict__ gamma, const float* __restrict__ beta,
    const float* __restrict__ Wc,
    ushort_t* __restrict__ Wt1, ushort_t* __restrict__ Wt2,
    float* __restrict__ pb1, float* __restrict__ pb2,
    float* __restrict__ pgamma, float* __restrict__ pbeta,
    float* __restrict__ pWc) {
  int bx = blockIdx.x;
  int t = threadIdx.x;
  if (bx < 3) {                 // Wt1: W1[768][256] -> Wt1[256][768]
    int k = bx * 256 + t;
    for (int c = 0; c < 256; c++)
      Wt1[(size_t)c * DIN + k] = f2bf(W1[(size_t)k * 256 + c]);
  } else if (bx == 3) {         // Wt2 with permuted k axis
    int k = t;
    int ko = orig_col(k);
    for (int c = 0; c < 256; c++)
      Wt2[(size_t)c * DH + k] = f2bf(W2[(size_t)ko * 256 + c]);
  } else {                      // permuted per-column vectors
    int o = orig_col(t);
    pb1[t] = b1[o];
    pb2[t] = b2[o];
    pgamma[t] = gamma[o];
    pbeta[t] = beta[o];
    pWc[t] = Wc[o];
  }
}

// ---------------- CSR build ----------------
__global__ void hist_kernel(const int* __restrict__ dst, int E, int* __restrict__ cnt) {
  for (int e = blockIdx.x * blockDim.x + threadIdx.x; e < E; e += gridDim.x * blockDim.x)
    atomicAdd(&cnt[dst[e]], 1);
}

__global__ __launch_bounds__(1024) void scan_kernel(const int* __restrict__ cnt,
                                                    int* __restrict__ row_off, int n) {
  __shared__ int s[1024];
  int t = threadIdx.x;
  int chunk = (n + 1023) / 1024;
  int lo = t * chunk, hi = min(lo + chunk, n);
  int sum = 0;
  for (int i = lo; i < hi; i++) sum += cnt[i];
  int mysum = sum;
  s[t] = sum;
  __syncthreads();
  for (int off = 1; off < 1024; off <<= 1) {
    int v = (t >= off) ? s[t - off] : 0;
    __syncthreads();
    s[t] += v;
    __syncthreads();
  }
  int run = s[t] - mysum;
  for (int i = lo; i < hi; i++) { row_off[i] = run; run += cnt[i]; }
  if (t == 1023) row_off[n] = s[1023];
}

__global__ void fill_kernel(const int* __restrict__ src, const int* __restrict__ dst, int E,
                            const int* __restrict__ row_off, int* __restrict__ fill,
                            int* __restrict__ col_src) {
  for (int e = blockIdx.x * blockDim.x + threadIdx.x; e < E; e += gridDim.x * blockDim.x) {
    int d = dst[e];
    int slot = row_off[d] + atomicAdd(&fill[d], 1);
    col_src[slot] = src[e];
  }
}

// ---------------- bf16 MFMA GEMM + fused alpha dots ----------------
// XCD-pairing block swizzle: co-locate the two col-blocks sharing an A panel
// on the same XCD (consecutive blocks round-robin XCDs). Identity on the
// partial tail chunk (bijection; ERRATA #11).
template <int K>
__global__ __launch_bounds__(256) void gemm_mfma(
    const ushort_t* __restrict__ A, const ushort_t* __restrict__ Bt,
    ushort_t* __restrict__ C, const float* __restrict__ a_s,
    const float* __restrict__ a_d, float* __restrict__ alpha_s,
    float* __restrict__ alpha_d, int Mreal) {
  __shared__ ushort_t lds[16384];  // A rows [0,8192) shorts, B rows [8192,16384)
  const int tid = threadIdx.x;
  const int lane = tid & 63;
  const int wave = tid >> 6;

  int p = blockIdx.y * 2 + blockIdx.x;
  int total = 2 * gridDim.y;
  int cch = p >> 4;
  int v;
  if ((cch << 4) + 16 <= total) {
    int r = p & 15;
    v = (cch << 4) | ((r & 7) << 1) | (r >> 3);
  } else {
    v = p;
  }
  const int col0 = (v & 1) * 128;
  const int row0 = (v >> 1) * 128;

  const int wr = wave >> 1, wc = wave & 1;
  const int c16 = lane & 15, g4 = lane >> 4;
  const int st_roff = lane >> 3;
  const int st_gsrc = (lane & 7) ^ st_roff;

  f32x4 acc[4][4];
#pragma unroll
  for (int m = 0; m < 4; m++)
#pragma unroll
    for (int nn = 0; nn < 4; nn++)
#pragma unroll
      for (int j = 0; j < 4; j++) acc[m][nn][j] = 0.f;

  for (int k0 = 0; k0 < K; k0 += 64) {
#pragma unroll
    for (int ci = 0; ci < 8; ci++) {
      int inst = wave * 8 + ci;
      int isB = inst >> 4;
      int idx = inst & 15;
      int lrow = idx * 8 + st_roff;
      const ushort_t* gsrc;
      if (isB == 0) {
        int rg = row0 + lrow;
        rg = rg < Mreal ? rg : Mreal - 1;
        gsrc = A + (size_t)rg * K + k0 + st_gsrc * 8;
      } else {
        gsrc = Bt + (size_t)(col0 + lrow) * K + k0 + st_gsrc * 8;
      }
      __builtin_amdgcn_global_load_lds(
          (const __attribute__((address_space(1))) void*)gsrc,
          (__attribute__((address_space(3))) void*)&lds[isB * 8192 + idx * 512],
          16, 0, 0);
    }
    __syncthreads();
#pragma unroll
    for (int ks = 0; ks < 2; ks++) {
      int g = ks * 4 + g4;
      short8v a[4], b[4];
#pragma unroll
      for (int m = 0; m < 4; m++) {
        int ra = wr * 64 + m * 16 + c16;
        a[m] = *(const short8v*)&lds[ra * 64 + (g ^ (ra & 7)) * 8];
      }
#pragma unroll
      for (int nn = 0; nn < 4; nn++) {
        int rb = wc * 64 + nn * 16 + c16;
        b[nn] = *(const short8v*)&lds[8192 + rb * 64 + (g ^ (rb & 7)) * 8];
      }
#pragma unroll
      for (int m = 0; m < 4; m++)
#pragma unroll
        for (int nn = 0; nn < 4; nn++)
          acc[m][nn] = __builtin_amdgcn_mfma_f32_16x16x32_bf16(a[m], b[nn],
                                                               acc[m][nn], 0, 0, 0);
    }
    __syncthreads();
  }

  float asv[4], adv[4];
#pragma unroll
  for (int nn = 0; nn < 4; nn++) {
    int col = col0 + wc * 64 + nn * 16 + c16;
    asv[nn] = a_s[col];
    adv[nn] = a_d[col];
  }

  uint* Cw = (uint*)C;
#pragma unroll
  for (int m = 0; m < 4; m++) {
    int row_base = row0 + wr * 64 + m * 16 + g4 * 4;
#pragma unroll
    for (int j = 0; j < 4; j++) {
      int row = row_base + j;
      float ps = 0.f, pd = 0.f;
#pragma unroll
      for (int nn = 0; nn < 4; nn++) {
        float v2 = acc[m][nn][j];
        ps = fmaf(v2, asv[nn], ps);
        pd = fmaf(v2, adv[nn], pd);
      }
#pragma unroll
      for (int o = 1; o < 16; o <<= 1) {
        ps += __shfl_xor(ps, o);
        pd += __shfl_xor(pd, o);
      }
      if (c16 == 0 && row < Mreal) {
        atomicAdd(&alpha_s[row], ps);
        atomicAdd(&alpha_d[row], pd);
      }
      if (row < Mreal) {
#pragma unroll
        for (int q = 0; q < 2; q++) {
          unsigned wv = (unsigned)f2bf(acc[m][2 * q][j]) |
                        ((unsigned)f2bf(acc[m][2 * q + 1][j]) << 16);
          Cw[(size_t)row * 128 + (col0 >> 1) + wc * 32 + q * 16 + c16] = wv;
        }
      }
    }
  }
}

// ---------------- GAT attention + aggregation (quarter-wave gather, 8-deep) ------
__global__ __launch_bounds__(256) void gat_agg(
    const ushort_t* __restrict__ hb, const float* __restrict__ as_,
    const float* __restrict__ ad_, const int* __restrict__ row_off,
    const int* __restrict__ col_src, const float* __restrict__ bias,
    ushort_t* __restrict__ outb, int n, int relu_out) {
  int node = blockIdx.x * 4 + (threadIdx.x >> 6);
  int lane = threadIdx.x & 63;
  if (node >= n) return;
  int lo = row_off[node], hi = row_off[node + 1];
  int deg = hi - lo;
  float adn = ad_[node];
  float self_e = leaky(as_[node] + adn);

  int cnt0 = min(deg, 64);
  int s0 = 0; float le0 = -3e38f;
  if (lane < cnt0) { s0 = col_src[lo + lane]; le0 = leaky(as_[s0] + adn); }

  // phase A: max
  float m = fmaxf(self_e, wave_max(le0));
  for (int base = 64; base < deg; base += 64) {
    int cnt = min(64, deg - base);
    float l2 = -3e38f;
    if (lane < cnt) l2 = leaky(as_[col_src[lo + base + lane]] + adn);
    m = fmaxf(m, wave_max(l2));
  }

  // phase B: sum of exp
  float z = wave_sum(lane < cnt0 ? __expf(le0 - m) : 0.f);
  for (int base = 64; base < deg; base += 64) {
    int cnt = min(64, deg - base);
    float ez = 0.f;
    if (lane < cnt) ez = __expf(leaky(as_[col_src[lo + base + lane]] + adn) - m);
    z += wave_sum(ez);
  }
  float ez_self = __expf(self_e - m);
  z += ez_self;
  float inv_z = 1.0f / z;

  // phase C: quarter-wave gather — each lane owns cols [l16*16, l16*16+16),
  // quarter q handles edge e+q; 8 rows in flight per wave.
  const int q = lane >> 4;
  const int l16 = lane & 15;
  const ushort_t* rowbase = hb + (size_t)l16 * 16;
  float acc[16];
  {
    const uint4* ps = (const uint4*)(rowbase + (size_t)node * 256);
    uint4 v0 = ps[0], v1 = ps[1];
    float ws = (q == 0) ? ez_self * inv_z : 0.f;
    float f[16];
    unpack8(v0, f);
    unpack8(v1, f + 8);
#pragma unroll
    for (int i = 0; i < 16; i++) acc[i] = ws * f[i];
  }

  auto gather = [&](int sreg, float lereg, int cnt) {
    int e = 0;
    for (; e + 8 <= cnt; e += 8) {
      int iA = e + q, iB = e + 4 + q;
      int sA = __shfl(sreg, iA);
      float lA = __shfl(lereg, iA);
      int sB = __shfl(sreg, iB);
      float lB = __shfl(lereg, iB);
      const uint4* pA = (const uint4*)(rowbase + (size_t)sA * 256);
      const uint4* pB = (const uint4*)(rowbase + (size_t)sB * 256);
      uint4 a0 = pA[0], a1 = pA[1];
      uint4 b0 = pB[0], b1 = pB[1];
      float wA = __expf(lA - m) * inv_z;
      float wB = __expf(lB - m) * inv_z;
      float f[16];
      unpack8(a0, f);
      unpack8(a1, f + 8);
#pragma unroll
      for (int i = 0; i < 16; i++) acc[i] = fmaf(wA, f[i], acc[i]);
      unpack8(b0, f);
      unpack8(b1, f + 8);
#pragma unroll
      for (int i = 0; i < 16; i++) acc[i] = fmaf(wB, f[i], acc[i]);
    }
    for (; e < cnt; e += 4) {
      int myE = e + q;
      int idx = myE < cnt ? myE : cnt - 1;
      int ss = __shfl(sreg, idx);
      float lee = __shfl(lereg, idx);
      float wgt = (myE < cnt) ? __expf(lee - m) * inv_z : 0.f;
      const uint4* pp = (const uint4*)(rowbase + (size_t)ss * 256);
      uint4 v0 = pp[0], v1 = pp[1];
      float f[16];
      unpack8(v0, f);
      unpack8(v1, f + 8);
#pragma unroll
      for (int i = 0; i < 16; i++) acc[i] = fmaf(wgt, f[i], acc[i]);
    }
  };
  gather(s0, le0, cnt0);
  for (int base = 64; base < deg; base += 64) {
    int cnt = min(64, deg - base);
    int s2 = 0; float le2 = -3e38f;
    if (lane < cnt) { s2 = col_src[lo + base + lane]; le2 = leaky(as_[s2] + adn); }
    gather(s2, le2, cnt);
  }

  // combine quarters
#pragma unroll
  for (int i = 0; i < 16; i++) {
    acc[i] += __shfl_xor(acc[i], 16);
    acc[i] += __shfl_xor(acc[i], 32);
  }

  if (q == 0) {
    float o[16];
#pragma unroll
    for (int i = 0; i < 16; i += 4) {
      float4 bb = *(const float4*)&bias[l16 * 16 + i];
      o[i]     = acc[i]     + bb.x;
      o[i + 1] = acc[i + 1] + bb.y;
      o[i + 2] = acc[i + 2] + bb.z;
      o[i + 3] = acc[i + 3] + bb.w;
    }
    if (relu_out) {
#pragma unroll
      for (int i = 0; i < 16; i++) o[i] = fmaxf(o[i], 0.f);
    }
    uint4* op = (uint4*)(outb + (size_t)node * 256 + l16 * 16);
    op[0] = pack8(o);
    op[1] = pack8(o + 8);
  }
}

// ---------------- BN stats (bf16 input, stored space) ----------------
__global__ __launch_bounds__(256) void bn_stats(const ushort_t* __restrict__ h, int n,
                                                float* __restrict__ bsum,
                                                float* __restrict__ bsq) {
  int c = threadIdx.x;
  int rows_per_block = (n + gridDim.x - 1) / gridDim.x;
  int r0 = blockIdx.x * rows_per_block;
  int r1 = min(r0 + rows_per_block, n);
  float sum = 0.f, sq = 0.f;
  for (int r = r0; r < r1; r++) {
    float v = bf2f(h[(size_t)r * 256 + c]);
    sum += v;
    sq = fmaf(v, v, sq);
  }
  atomicAdd(&bsum[c], sum);
  atomicAdd(&bsq[c], sq);
}

// ---------------- BN apply + ReLU (bf16 -> bf16, stored space) ----------------
__global__ __launch_bounds__(256) void bn_apply(const ushort_t* __restrict__ h,
                                                const float* __restrict__ bsum,
                                                const float* __restrict__ bsq,
                                                const float* __restrict__ gamma,
                                                const float* __restrict__ beta,
                                                ushort_t* __restrict__ h2b, int n) {
  int total4 = n * 64;
  float inv_n = 1.0f / (float)n;
  for (int f = blockIdx.x * blockDim.x + threadIdx.x; f < total4;
       f += gridDim.x * blockDim.x) {
    int c4 = f & 63;
    uint2 hv = ((const uint2*)h)[f];
    float v0, v1, v2, v3;
    {
      union { unsigned u; float fl; } t;
      t.u = hv.x << 16;         v0 = t.fl;
      t.u = hv.x & 0xFFFF0000u; v1 = t.fl;
      t.u = hv.y << 16;         v2 = t.fl;
      t.u = hv.y & 0xFFFF0000u; v3 = t.fl;
    }
    float4 sm = ((const float4*)bsum)[c4];
    float4 sl = ((const float4*)bsq)[c4];
    float4 g = ((const float4*)gamma)[c4];
    float4 bb = ((const float4*)beta)[c4];
    float m, var;
    m = sm.x * inv_n; var = sl.x * inv_n - m * m;
    v0 = fmaxf(g.x * (v0 - m) * rsqrtf(var + 1e-5f) + bb.x, 0.f);
    m = sm.y * inv_n; var = sl.y * inv_n - m * m;
    v1 = fmaxf(g.y * (v1 - m) * rsqrtf(var + 1e-5f) + bb.y, 0.f);
    m = sm.z * inv_n; var = sl.z * inv_n - m * m;
    v2 = fmaxf(g.z * (v2 - m) * rsqrtf(var + 1e-5f) + bb.z, 0.f);
    m = sm.w * inv_n; var = sl.w * inv_n - m * m;
    v3 = fmaxf(g.w * (v3 - m) * rsqrtf(var + 1e-5f) + bb.w, 0.f);
    uint2 o;
    o.x = (unsigned)f2bf(v0) | ((unsigned)f2bf(v1) << 16);
    o.y = (unsigned)f2bf(v2) | ((unsigned)f2bf(v3) << 16);
    ((uint2*)h2b)[f] = o;
  }
}

// ---------------- mean pool: partial sums ----------------
__device__ inline int lower_bound_dev(const int* a, int n, int v) {
  int lo = 0, hi = n;
  while (lo < hi) {
    int mid = (lo + hi) >> 1;
    if (a[mid] < v) lo = mid + 1; else hi = mid;
  }
  return lo;
}

#define POOL_CHUNKS 16
__global__ __launch_bounds__(256) void pool_partial(const ushort_t* __restrict__ h,
                                                    const int* __restrict__ batch, int n,
                                                    float* __restrict__ psum) {
  int g = blockIdx.x / POOL_CHUNKS;
  int c = blockIdx.x % POOL_CHUNKS;
  int lo = lower_bound_dev(batch, n, g);
  int hi = lower_bound_dev(batch, n, g + 1);
  int len = hi - lo;
  int r0 = lo + (int)(((long long)len * c) / POOL_CHUNKS);
  int r1 = lo + (int)(((long long)len * (c + 1)) / POOL_CHUNKS);
  if (r1 <= r0) return;
  float sum = 0.f;
  for (int r = r0; r < r1; r++) sum += bf2f(h[(size_t)r * 256 + threadIdx.x]);
  atomicAdd(&psum[(size_t)g * 256 + threadIdx.x], sum);
}

// ---------------- final head (pooled part uses permuted Wc) ----------------
__global__ __launch_bounds__(256) void final_kernel(const float* __restrict__ psum,
                                                    const int* __restrict__ batch, int n,
                                                    const float* __restrict__ ce,
                                                    const float* __restrict__ pWc,
                                                    const float* __restrict__ Wc,
                                                    const float* __restrict__ bc,
                                                    float* __restrict__ out, int B) {
  int g = blockIdx.x;
  int t = threadIdx.x;
  int lo = lower_bound_dev(batch, n, g);
  int hi = lower_bound_dev(batch, n, g + 1);
  float inv_cnt = 1.0f / fmaxf((float)(hi - lo), 1.0f);
  float p = 0.f;
  p = fmaf(psum[(size_t)g * 256 + t] * inv_cnt, pWc[t], p);
  p = fmaf(ce[(size_t)g * 768 + t],        Wc[256 + t], p);
  p = fmaf(ce[(size_t)g * 768 + 256 + t],  Wc[512 + t], p);
  p = fmaf(ce[(size_t)g * 768 + 512 + t],  Wc[768 + t], p);
  __shared__ float red[256];
  red[t] = p;
  __syncthreads();
  for (int s = 128; s; s >>= 1) {
    if (t < s) red[t] += red[t + s];
    __syncthreads();
  }
  if (t == 0) out[g] = red[0] + bc[0];
}

// ---------------- launch ----------------
extern "C" void kernel_launch(void* const* d_in, const int* in_sizes, int n_in,
                              void* d_out, int out_size, void* d_ws, size_t ws_size,
                              hipStream_t stream) {
  const float* ce    = (const float*)d_in[0];
  const float* x     = (const float*)d_in[1];
  const int*   edge  = (const int*)d_in[2];
  const int*   batch = (const int*)d_in[3];
  const float* W1    = (const float*)d_in[4];
  const float* a_s1  = (const float*)d_in[5];
  const float* a_d1  = (const float*)d_in[6];
  const float* b1    = (const float*)d_in[7];
  const float* W2    = (const float*)d_in[8];
  const float* a_s2  = (const float*)d_in[9];
  const float* a_d2  = (const float*)d_in[10];
  const float* b2    = (const float*)d_in[11];
  const float* gamma = (const float*)d_in[12];
  const float* beta  = (const float*)d_in[13];
  const float* Wc    = (const float*)d_in[14];
  const float* bc    = (const float*)d_in[15];

  const int B = in_sizes[0] / DIN;
  const int n = in_sizes[1] / DIN;
  const int E = in_sizes[2] / 2;
  const int* esrc = edge;
  const int* edst = edge + E;

  char* w = (char*)d_ws;
  size_t off = 0;
  auto carve = [&](size_t bytes) -> void* {
    void* p = w + off;
    off = (off + bytes + 255) & ~(size_t)255;
    return p;
  };
  size_t hbytes = (size_t)n * DH * 2;            // 25.6 MB
  char*  R1      = (char*)carve((size_t)n * DIN * 2);
  ushort_t* xb    = (ushort_t*)R1;
  ushort_t* h1b   = (ushort_t*)R1;
  ushort_t* h2b   = (ushort_t*)(R1 + hbytes);
  ushort_t* buf_ob = (ushort_t*)(R1 + 2 * hbytes);
  ushort_t* buf_hb = (ushort_t*)carve(hbytes);   // GEMM output (both layers)
  int*   row_off = (int*)carve((size_t)(n + 1) * 4);
  int*   col_src = (int*)carve((size_t)E * 4);
  ushort_t* Wt1  = (ushort_t*)carve((size_t)DIN * DH * 2);
  ushort_t* Wt2  = (ushort_t*)carve((size_t)DH * DH * 2);
  float* pb1     = (float*)carve(DH * 4);
  float* pb2     = (float*)carve(DH * 4);
  float* pgamma  = (float*)carve(DH * 4);
  float* pbeta   = (float*)carve(DH * 4);
  float* pWc     = (float*)carve(DH * 4);
  char* zero0 = (char*)carve((size_t)n * 4);     // cnt
  int*   cnt     = (int*)zero0;
  int*   fill    = (int*)carve((size_t)n * 4);
  float* as1buf  = (float*)carve((size_t)n * 4);
  float* ad1buf  = (float*)carve((size_t)n * 4);
  float* as2buf  = (float*)carve((size_t)n * 4);
  float* ad2buf  = (float*)carve((size_t)n * 4);
  float* bn_sum  = (float*)carve(DH * 4);
  float* bn_sq   = (float*)carve(DH * 4);
  float* psum    = (float*)carve((size_t)B * DH * 4);
  size_t zero_bytes = (size_t)((char*)(psum + (size_t)B * DH) - zero0);

  hipMemsetAsync(zero0, 0, zero_bytes, stream);

  const int gN4 = (n + 3) / 4;
  const int Mb = (n + 127) / 128;

  prep_kernel<<<5, 256, 0, stream>>>(W1, W2, b1, b2, gamma, beta, Wc,
                                     Wt1, Wt2, pb1, pb2, pgamma, pbeta, pWc);
  relxb_kernel<<<gN4, 256, 0, stream>>>(ce, x, batch, xb, n);
  hist_kernel<<<1024, 256, 0, stream>>>(edst, E, cnt);
  scan_kernel<<<1, 1024, 0, stream>>>(cnt, row_off, n);
  fill_kernel<<<1024, 256, 0, stream>>>(esrc, edst, E, row_off, fill, col_src);

  // ---- layer 1 ----
  gemm_mfma<DIN><<<dim3(2, Mb), 256, 0, stream>>>(xb, Wt1, buf_hb, a_s1, a_d1,
                                                  as1buf, ad1buf, n);
  gat_agg<<<gN4, 256, 0, stream>>>(buf_hb, as1buf, ad1buf, row_off, col_src, pb1,
                                   h1b, n, 0);
  bn_stats<<<512, 256, 0, stream>>>(h1b, n, bn_sum, bn_sq);
  bn_apply<<<2048, 256, 0, stream>>>(h1b, bn_sum, bn_sq, pgamma, pbeta, h2b, n);

  // ---- layer 2 ----
  gemm_mfma<DH><<<dim3(2, Mb), 256, 0, stream>>>(h2b, Wt2, buf_hb, a_s2, a_d2,
                                                 as2buf, ad2buf, n);
  gat_agg<<<gN4, 256, 0, stream>>>(buf_hb, as2buf, ad2buf, row_off, col_src, pb2,
                                   buf_ob, n, 1);

  // ---- head ----
  pool_partial<<<B * POOL_CHUNKS, 256, 0, stream>>>(buf_ob, batch, n, psum);
  final_kernel<<<B, 256, 0, stream>>>(psum, batch, n, ce, pWc, Wc, bc,
                                      (float*)d_out, B);
}